// Round 6
// baseline (374.002 us; speedup 1.0000x reference)
//
#include <hip/hip_runtime.h>
#include <stdint.h>

#define N 384
#define NR (N*N)        // 147456
#define PL (NR + 64)    // padded plane stride
#define C 128
#define WSZ 16384       // 128x128 elements per weight

typedef unsigned short ushort_t;
typedef __attribute__((ext_vector_type(8))) _Float16 f16x8;
typedef __attribute__((ext_vector_type(4))) float f32x4;

// ---- fp16 converts (internal pipeline dtype) ---------------------------
__device__ __forceinline__ ushort_t f2h(float f) {
  union { _Float16 h; ushort_t u; } v; v.h = (_Float16)f; return v.u;
}
__device__ __forceinline__ float h2f(ushort_t u) {
  union { _Float16 h; ushort_t u; } v; v.u = u; return (float)v.h;
}
__device__ __forceinline__ void unpack8h(uint4 q, float f[8]) {
  union { uint4 q; _Float16 h[8]; } v; v.q = q;
#pragma unroll
  for (int e = 0; e < 8; ++e) f[e] = (float)v.h[e];
}
__device__ __forceinline__ uint4 pack8h(const float f[8]) {
  union { uint4 q; _Float16 h[8]; } v;
#pragma unroll
  for (int e = 0; e < 8; ++e) v.h[e] = (_Float16)f[e];
  return v.q;
}

// ---- bf16 converts (only for bf16 external-dtype fallback IO) ----------
__device__ __forceinline__ float bf2f(ushort_t u) {
  union { unsigned int i; float f; } v; v.i = ((unsigned int)u) << 16; return v.f;
}
__device__ __forceinline__ ushort_t f2bf(float f) {
  union { float f; unsigned int i; } v; v.f = f;
  unsigned int u = v.i + 0x7FFF + ((v.i >> 16) & 1);
  return (ushort_t)(u >> 16);
}
__device__ __forceinline__ void unpack8bf(uint4 q, float f[8]) {
  const unsigned int* w = (const unsigned int*)&q;
#pragma unroll
  for (int e = 0; e < 4; ++e) {
    f[2*e]   = bf2f((ushort_t)(w[e] & 0xffffu));
    f[2*e+1] = bf2f((ushort_t)(w[e] >> 16));
  }
}
__device__ __forceinline__ uint4 pack8bf(const float f[8]) {
  uint4 q;
  unsigned int* w = (unsigned int*)&q;
#pragma unroll
  for (int e = 0; e < 4; ++e)
    w[e] = (unsigned int)f2bf(f[2*e]) | ((unsigned int)f2bf(f[2*e+1]) << 16);
  return q;
}

// v_rcp: ~1 ulp, replaces the ~10-op exact-divide sequence (no fast-math)
__device__ __forceinline__ float sigmoidf_(float x) {
  return __builtin_amdgcn_rcpf(1.0f + __expf(-x));
}

// ---- dtype-dual IO helpers (isf32 is wave-uniform) ---------------------
__device__ __forceinline__ void load8f(const void* p, size_t idx, int isf32, float f[8]) {
  if (isf32) {
    const float* q = (const float*)p + idx;
    const float4 a = ((const float4*)q)[0];
    const float4 b = ((const float4*)q)[1];
    f[0]=a.x; f[1]=a.y; f[2]=a.z; f[3]=a.w;
    f[4]=b.x; f[5]=b.y; f[6]=b.z; f[7]=b.w;
  } else {
    unpack8bf(*(const uint4*)((const ushort_t*)p + idx), f);
  }
}
__device__ __forceinline__ void store8(void* p, size_t idx, int isf32, const float f[8]) {
  if (isf32) {
    float* q = (float*)p + idx;
    ((float4*)q)[0] = make_float4(f[0], f[1], f[2], f[3]);
    ((float4*)q)[1] = make_float4(f[4], f[5], f[6], f[7]);
  } else {
    *(uint4*)((ushort_t*)p + idx) = pack8bf(f);
  }
}
__device__ __forceinline__ void store1(void* p, size_t idx, int isf32, float v) {
  if (isf32) ((float*)p)[idx] = v;
  else       ((ushort_t*)p)[idx] = f2bf(v);
}

// ---- weight prep + inline dtype detection ------------------------------
__global__ void kprep(const unsigned int* __restrict__ zw,
                      const void* __restrict__ Wa1, const void* __restrict__ Wa2,
                      const void* __restrict__ Wb1, const void* __restrict__ Wb2,
                      const void* __restrict__ Wg,  const void* __restrict__ Wout,
                      ushort_t* __restrict__ wp, int* __restrict__ flag)
{
  const int t = threadIdx.x;
  __shared__ int cnt[4];
  {
    unsigned int u = zw[t];
    int e = (u >> 23) & 0xFF;
    int sane = (e >= 87 && e <= 132) ? 1 : 0;
    unsigned long long b = __ballot(sane);
    if ((t & 63) == 0) cnt[t >> 6] = __popcll(b);
  }
  __syncthreads();
  const int isf32 = ((cnt[0] + cnt[1] + cnt[2] + cnt[3]) >= 128) ? 1 : 0;
  if (blockIdx.x == 0 && t == 0) flag[0] = isf32;

  const void* src;
  switch (blockIdx.x) {
    case 0: src = Wa1; break;
    case 1: src = Wa2; break;
    case 2: src = Wb1; break;
    case 3: src = Wb2; break;
    case 4: src = Wg;  break;
    default: src = Wout; break;
  }
  ushort_t* dst = wp + (size_t)blockIdx.x * WSZ;
  for (int c = t; c < 2048; c += 256) {
    int ks = c >> 9, nf = (c >> 6) & 7, lane = c & 63;
    int quad = lane >> 4, l16 = lane & 15;
    size_t sidx = (size_t)(nf*16 + l16)*128 + ks*32 + quad*8;
    float f[8]; load8f(src, sidx, isf32, f);
    *(uint4*)(dst + (size_t)c*8) = pack8h(f);
  }
}

// ---------------- K1: fused LN(z) + 5 projections -----------------------
// Register hunt v3: two-pass LN (no 16-reg z cache; pass2 re-reads L3-hot
// z) + QUARTER acc (16 live: a1[2]+a2[2] per nf, unroll 1). If VGPR still
// ~124 after this, pressure is NOT acc/LN regs (falsifies hypothesis).
__global__ __launch_bounds__(256, 2)
void k1(const void* __restrict__ z, const void* __restrict__ gin,
        const void* __restrict__ bin, const ushort_t* __restrict__ wp,
        ushort_t* __restrict__ a_t, ushort_t* __restrict__ b_t,
        void* __restrict__ gout, ushort_t* __restrict__ g_t, int gIsWs,
        const int* __restrict__ flag)
{
  __shared__ ushort_t tb[128*72];      // 18 KB: 128 d x 64 rows (+pad to 72)
  const int t = threadIdx.x;
  const int isf32 = *flag;
  const int wave = t >> 6, lane = t & 63;
  const int quad = lane >> 4, l16 = lane & 15;
  const int rg = wave >> 1, ch = wave & 1;
  const int R0 = blockIdx.x * 64;
  const f32x4 z4 = {0.f, 0.f, 0.f, 0.f};

  // ---- A-fragments via two-pass layernorm (fp32 stats on raw z)
  f16x8 af[2][4];
#pragma unroll
  for (int mf = 0; mf < 2; ++mf) {
    const int row = R0 + rg*32 + mf*16 + l16;
    float s = 0.f, q = 0.f;
#pragma unroll
    for (int ks = 0; ks < 4; ++ks) {
      float x[8];
      load8f(z, (size_t)row*C + ks*32 + quad*8, isf32, x);
#pragma unroll
      for (int e = 0; e < 8; ++e) { s += x[e]; q += x[e]*x[e]; }
    }
    s += __shfl_xor(s, 16); s += __shfl_xor(s, 32);
    q += __shfl_xor(q, 16); q += __shfl_xor(q, 32);
    const float mu = s * 0.0078125f;
    const float rstd = rsqrtf(q * 0.0078125f - mu*mu + 1e-5f);
#pragma unroll
    for (int ks = 0; ks < 4; ++ks) {
      float x[8], ga[8], be[8];
      load8f(z, (size_t)row*C + ks*32 + quad*8, isf32, x);   // L3-hot re-read
      load8f(gin, (size_t)(ks*32 + quad*8), isf32, ga);
      load8f(bin, (size_t)(ks*32 + quad*8), isf32, be);
      union { alignas(16) _Float16 h[8]; f16x8 v; } u;
#pragma unroll
      for (int e = 0; e < 8; ++e)
        u.h[e] = (_Float16)((x[e] - mu) * rstd * ga[e] + be[e]);
      af[mf][ks] = u.v;
    }
  }

  // ---- gated pair projection: dst[d][R] = sig(z@W1^T) * (z@W2^T)
  // nf quarters sequential (unroll 1): only 16 acc live.
  auto pair = [&](const ushort_t* W1p, const ushort_t* W2p, ushort_t* dst) {
#pragma unroll 1
    for (int nf = 0; nf < 4; ++nf) {
      f32x4 a1[2], a2[2];
      a1[0] = z4; a1[1] = z4; a2[0] = z4; a2[1] = z4;
#pragma unroll
      for (int ks = 0; ks < 4; ++ks) {
        const size_t foff = (size_t)((ks*8 + ch*4 + nf)*64 + lane) * 8;
        f16x8 b1 = *(const f16x8*)(W1p + foff);
        f16x8 b2 = *(const f16x8*)(W2p + foff);
#pragma unroll
        for (int mf = 0; mf < 2; ++mf) {
          a1[mf] = __builtin_amdgcn_mfma_f32_16x16x32_f16(af[mf][ks], b1, a1[mf], 0, 0, 0);
          a2[mf] = __builtin_amdgcn_mfma_f32_16x16x32_f16(af[mf][ks], b2, a2[mf], 0, 0, 0);
        }
      }
#pragma unroll
      for (int mf = 0; mf < 2; ++mf)
#pragma unroll
        for (int r = 0; r < 4; ++r) {
          int rowl = rg*32 + mf*16 + quad*4 + r;       // 0..64
          int col  = ch*64 + nf*16 + l16;              // 0..128 (the d index)
          tb[col*72 + rowl] = f2h(a2[mf][r] * sigmoidf_(a1[mf][r]));
        }
    }
    // LDS-write visibility only; no vmcnt drain (a_t/b_t stores fly on)
    asm volatile("s_waitcnt lgkmcnt(0)" ::: "memory");
    __builtin_amdgcn_s_barrier();
#pragma unroll
    for (int i = 0; i < 4; ++i) {
      int cid = t + i*256, dl = cid >> 3, rc = cid & 7;  // 128 d x 8 chunks
      uint4 v = *(const uint4*)(tb + dl*72 + rc*8);
      *(uint4*)(dst + (size_t)dl*PL + R0 + rc*8) = v;
    }
    // tb reads consumed before the store issues (compiler lgkmcnt);
    // barrier alone protects tb reuse by the next pair.
    asm volatile("" ::: "memory");
    __builtin_amdgcn_s_barrier();
  };
  pair(wp + 0*WSZ, wp + 1*WSZ, a_t);
  pair(wp + 2*WSZ, wp + 3*WSZ, b_t);

  // ---- g = sigmoid(z@Wg^T), natural [R][d] layout (16 acc live)
  {
    const ushort_t* Wgp = wp + 4*WSZ;
#pragma unroll 1
    for (int nf = 0; nf < 4; ++nf) {
      f32x4 ag[2];
      ag[0] = z4; ag[1] = z4;
#pragma unroll
      for (int ks = 0; ks < 4; ++ks) {
        const size_t foff = (size_t)((ks*8 + ch*4 + nf)*64 + lane) * 8;
        f16x8 b = *(const f16x8*)(Wgp + foff);
#pragma unroll
        for (int mf = 0; mf < 2; ++mf)
          ag[mf] = __builtin_amdgcn_mfma_f32_16x16x32_f16(af[mf][ks], b, ag[mf], 0, 0, 0);
      }
#pragma unroll
      for (int mf = 0; mf < 2; ++mf)
#pragma unroll
        for (int r = 0; r < 4; ++r) {
          int row = R0 + rg*32 + mf*16 + quad*4 + r;
          int col = ch*64 + nf*16 + l16;
          float v = sigmoidf_(ag[mf][r]);
          size_t idx = (size_t)row*C + col;
          if (gIsWs) g_t[idx] = f2h(v);
          else       store1(gout, idx, isf32, v);
        }
    }
  }
}

// ---------------- K2: s_d = A_d * B_d^T per channel ---------------------
// LDS double-buffer: MFMA-first ordering, ONE lgkm-only barrier per kt
// (was 2), global prefetch 2 tiles deep. 64 KB LDS -> 2 blocks/CU.
// Hazards: writes always target the opposite buffer from all in-flight
// reads; prior-tile reads fenced by previous iteration's barrier.
__global__ __launch_bounds__(256, 2)
void k2(const ushort_t* __restrict__ a_t, const ushort_t* __restrict__ b_t,
        ushort_t* __restrict__ s_t)
{
  __shared__ ushort_t As[2][128*64];
  __shared__ ushort_t Bs[2][128*64];
  const int t = threadIdx.x;
  const int wave = t >> 6, lane = t & 63;
  const int quad = lane >> 4, l16 = lane & 15;
  const int wm = wave >> 1, wn = wave & 1;
  const int lin = blockIdx.x;
  const int xcd = lin & 7, slot = lin >> 3;
  const int d = xcd + 8*(slot/9);
  const int tile = slot - (slot/9)*9;
  const int i0 = (tile/3) * 128, j0 = (tile%3) * 128;
  const size_t dbase = (size_t)d * PL;

  f32x4 acc[4][4];
  const f32x4 z4 = {0.f, 0.f, 0.f, 0.f};
#pragma unroll
  for (int mf = 0; mf < 4; ++mf)
#pragma unroll
    for (int nf = 0; nf < 4; ++nf) acc[mf][nf] = z4;

  uint4 va[4], vb[4];
  // ---- prologue: tile0 -> buf0; tile1 -> regs
#pragma unroll
  for (int j = 0; j < 4; ++j) {
    int cid = t + j*256, row = cid >> 3, c = cid & 7;
    va[j] = *(const uint4*)(a_t + dbase + (size_t)(i0 + row)*N + c*8);
    vb[j] = *(const uint4*)(b_t + dbase + (size_t)(j0 + row)*N + c*8);
  }
#pragma unroll
  for (int j = 0; j < 4; ++j) {
    int cid = t + j*256, row = cid >> 3, c = cid & 7;
    int p = c ^ (row & 7);
    *(uint4*)(&As[0][0] + row*64 + p*8) = va[j];
    *(uint4*)(&Bs[0][0] + row*64 + p*8) = vb[j];
  }
#pragma unroll
  for (int j = 0; j < 4; ++j) {
    int cid = t + j*256, row = cid >> 3, c = cid & 7;
    va[j] = *(const uint4*)(a_t + dbase + (size_t)(i0 + row)*N + 64 + c*8);
    vb[j] = *(const uint4*)(b_t + dbase + (size_t)(j0 + row)*N + 64 + c*8);
  }
  asm volatile("s_waitcnt lgkmcnt(0)" ::: "memory");
  __builtin_amdgcn_s_barrier();

  for (int kt = 0; kt < 6; ++kt) {
    const int cur = kt & 1;
    const ushort_t* Ab = &As[cur][0];
    const ushort_t* Bb = &Bs[cur][0];
    // ---- MFMA on tile kt (staged & visible)
#pragma unroll
    for (int ks = 0; ks < 2; ++ks) {
      f16x8 afr[4], bfr[4];
#pragma unroll
      for (int f = 0; f < 4; ++f) {
        int ra = wm*64 + f*16 + l16;
        int pa = (ks*4 + quad) ^ (ra & 7);
        afr[f] = *(const f16x8*)(Ab + ra*64 + pa*8);
        int rb = wn*64 + f*16 + l16;
        int pb = (ks*4 + quad) ^ (rb & 7);
        bfr[f] = *(const f16x8*)(Bb + rb*64 + pb*8);
      }
#pragma unroll
      for (int mf = 0; mf < 4; ++mf)
#pragma unroll
        for (int nf = 0; nf < 4; ++nf)
          acc[mf][nf] = __builtin_amdgcn_mfma_f32_16x16x32_f16(afr[mf], bfr[nf], acc[mf][nf], 0, 0, 0);
    }
    if (kt < 5) {
      // ---- stage tile kt+1 (regs -> opposite buffer); vmcnt wait was
      //      covered by the MFMA phase above
      ushort_t* Aw = &As[cur ^ 1][0];
      ushort_t* Bw = &Bs[cur ^ 1][0];
#pragma unroll
      for (int j = 0; j < 4; ++j) {
        int cid = t + j*256, row = cid >> 3, c = cid & 7;
        int p = c ^ (row & 7);
        *(uint4*)(Aw + row*64 + p*8) = va[j];
        *(uint4*)(Bw + row*64 + p*8) = vb[j];
      }
      if (kt < 4) {
        // ---- prefetch tile kt+2 into regs (flies across the barrier)
#pragma unroll
        for (int j = 0; j < 4; ++j) {
          int cid = t + j*256, row = cid >> 3, c = cid & 7;
          va[j] = *(const uint4*)(a_t + dbase + (size_t)(i0 + row)*N + (kt+2)*64 + c*8);
          vb[j] = *(const uint4*)(b_t + dbase + (size_t)(j0 + row)*N + (kt+2)*64 + c*8);
        }
      }
      asm volatile("s_waitcnt lgkmcnt(0)" ::: "memory");  // ds_writes + reads drained
      __builtin_amdgcn_s_barrier();
    }
  }
#pragma unroll
  for (int mf = 0; mf < 4; ++mf)
#pragma unroll
    for (int nf = 0; nf < 4; ++nf)
#pragma unroll
      for (int r = 0; r < 4; ++r) {
        int row = wm*64 + mf*16 + quad*4 + r;
        int col = wn*64 + nf*16 + l16;
        s_t[dbase + (size_t)(i0 + row)*N + j0 + col] = f2h(acc[mf][nf][r]);
      }
}

// ---------------- K3: out = g * (LN(s) @ Wout^T) ------------------------
// (R5 structure: two-pass LN, A-frags preloaded, 2 sequential nf-halves,
// lgkm-only barriers. Neutral vs R4 but reg-lighter; keep.)
__global__ __launch_bounds__(256, 2)
void k3(const ushort_t* __restrict__ s_t, const void* __restrict__ gno,
        const void* __restrict__ bno, const ushort_t* __restrict__ wp,
        void* __restrict__ io, const ushort_t* __restrict__ g_t, int gIsWs,
        const int* __restrict__ flag)
{
  __shared__ ushort_t ss[128*136];
  const int t = threadIdx.x;
  const int isf32 = *flag;
  const int wave = t >> 6, lane = t & 63;
  const int quad = lane >> 4, l16 = lane & 15;
  const int R0 = blockIdx.x * 128;
  const ushort_t* Woutp = wp + 5*WSZ;

  // stage s tile [d][R] -> LDS [R][d] via 8x8 register transpose
  {
    const int dg = t >> 4, rg = t & 15;
    const int d0 = dg * 8;
    uint4 v[8];
#pragma unroll
    for (int dd = 0; dd < 8; ++dd)
      v[dd] = *(const uint4*)(s_t + (size_t)(d0 + dd)*PL + R0 + rg*8);
    const ushort_t* sv = (const ushort_t*)v;
#pragma unroll
    for (int rr0 = 0; rr0 < 8; ++rr0) {
      int rr = (rr0 + (t & 7)) & 7;          // lane stagger: kills bank conflicts
      ushort_t w[8];
#pragma unroll
      for (int dd = 0; dd < 8; ++dd) w[dd] = sv[dd*8 + rr];
      *(uint4*)(ss + (rg*8 + rr)*136 + d0) = *(const uint4*)w;
    }
  }
  asm volatile("s_waitcnt lgkmcnt(0)" ::: "memory");
  __builtin_amdgcn_s_barrier();

  // layernorm over d (2 threads per row), TWO-PASS over LDS (reg-light)
  {
    const int r = t >> 1, h = t & 1;
    float sum = 0.f, sq = 0.f;
#pragma unroll
    for (int j = 0; j < 8; ++j) {
      uint4 q = *(const uint4*)(ss + r*136 + (h*8 + j)*8);
      float f[8]; unpack8h(q, f);
#pragma unroll
      for (int e = 0; e < 8; ++e) { sum += f[e]; sq += f[e]*f[e]; }
    }
    sum += __shfl_xor(sum, 1);
    sq  += __shfl_xor(sq, 1);
    const float mu = sum * 0.0078125f;
    const float rstd = rsqrtf(sq * 0.0078125f - mu*mu + 1e-5f);
#pragma unroll
    for (int j = 0; j < 8; ++j) {
      const int g = h*8 + j;
      uint4 q = *(const uint4*)(ss + r*136 + g*8);
      float f[8], gm[8], bt[8];
      unpack8h(q, f);
      load8f(gno, (size_t)g*8, isf32, gm);
      load8f(bno, (size_t)g*8, isf32, bt);
#pragma unroll
      for (int e = 0; e < 8; ++e) f[e] = (f[e] - mu) * rstd * gm[e] + bt[e];
      *(uint4*)(ss + r*136 + g*8) = pack8h(f);
    }
  }
  asm volatile("s_waitcnt lgkmcnt(0)" ::: "memory");  // LN writes visible
  __builtin_amdgcn_s_barrier();

  // load ALL A-fragments first (16 regs), then barrier so the per-half
  // h write-back below can't race any wave's fragment reads.
  f16x8 afr[2][4];
#pragma unroll
  for (int ks = 0; ks < 4; ++ks)
#pragma unroll
    for (int mf = 0; mf < 2; ++mf) {
      int row = wave*32 + mf*16 + l16;
      afr[mf][ks] = *(const f16x8*)(ss + row*136 + (ks*4 + quad)*8);
    }
  asm volatile("s_waitcnt lgkmcnt(0)" ::: "memory");  // all frag reads done
  __builtin_amdgcn_s_barrier();

  // GEMM in two sequential nf-halves; write each half's h straight to ss
  const f32x4 z4 = {0.f, 0.f, 0.f, 0.f};
#pragma unroll 1
  for (int nh = 0; nh < 2; ++nh) {
    f32x4 acc[2][4];
#pragma unroll
    for (int mf = 0; mf < 2; ++mf)
#pragma unroll
      for (int nn = 0; nn < 4; ++nn) acc[mf][nn] = z4;
#pragma unroll
    for (int ks = 0; ks < 4; ++ks)
#pragma unroll
      for (int nn = 0; nn < 4; ++nn) {
        size_t foff = (size_t)(((ks*8 + nh*4 + nn)*64 + lane)) * 8;
        f16x8 b = *(const f16x8*)(Woutp + foff);
#pragma unroll
        for (int mf = 0; mf < 2; ++mf)
          acc[mf][nn] = __builtin_amdgcn_mfma_f32_16x16x32_f16(afr[mf][ks], b, acc[mf][nn], 0, 0, 0);
      }
#pragma unroll
    for (int mf = 0; mf < 2; ++mf)
#pragma unroll
      for (int nn = 0; nn < 4; ++nn)
#pragma unroll
        for (int r = 0; r < 4; ++r) {
          int row = wave*32 + mf*16 + quad*4 + r;
          int col = (nh*4 + nn)*16 + l16;
          ss[row*136 + col] = f2h(acc[mf][nn][r]);
        }
  }
  asm volatile("s_waitcnt lgkmcnt(0)" ::: "memory");  // h writes visible
  __builtin_amdgcn_s_barrier();

  // gated store: out = g * h, fully vectorized
#pragma unroll
  for (int i = 0; i < 8; ++i) {
    int cid = t + i*256;
    int row = cid >> 4, ch = cid & 15;
    size_t idx = (size_t)(R0 + row)*C + ch*8;
    float gf[8], hf[8], of[8];
    if (gIsWs) unpack8h(*(const uint4*)(g_t + idx), gf);
    else       load8f(io, idx, isf32, gf);
    unpack8h(*(const uint4*)(ss + row*136 + ch*8), hf);
#pragma unroll
    for (int e = 0; e < 8; ++e) of[e] = gf[e] * hf[e];
    store8(io, idx, isf32, of);
  }
}

extern "C" void kernel_launch(void* const* d_in, const int* in_sizes, int n_in,
                              void* d_out, int out_size, void* d_ws, size_t ws_size,
                              hipStream_t stream) {
  (void)in_sizes; (void)n_in; (void)out_size;
  const void* z    = d_in[0];
  const void* gin  = d_in[1];
  const void* bin  = d_in[2];
  const void* gno  = d_in[3];
  const void* bno  = d_in[4];
  const void* Wa1  = d_in[5];
  const void* Wa2  = d_in[6];
  const void* Wb1  = d_in[7];
  const void* Wb2  = d_in[8];
  const void* Wg   = d_in[9];
  const void* Wout = d_in[10];

  const size_t plane = (size_t)C * PL;                         // padded [d][R] plane
  int* flag     = (int*)d_ws;                                  // 256 B
  ushort_t* wp  = (ushort_t*)((char*)d_ws + 256);              // 6 x 32 KB
  ushort_t* a_t = wp + (size_t)6*WSZ;
  ushort_t* b_t = a_t + plane;
  ushort_t* s_t = b_t + plane;
  ushort_t* g_t = s_t + plane;
  size_t need_g = 256 + (size_t)6*WSZ*2 + (3*plane + (size_t)NR*C)*2;
  int gIsWs = (ws_size >= need_g) ? 1 : 0;

  kprep<<<6, 256, 0, stream>>>((const unsigned int*)z, Wa1, Wa2, Wb1, Wb2, Wg, Wout, wp, flag);
  k1<<<NR/64, 256, 0, stream>>>(z, gin, bin, wp, a_t, b_t, d_out, g_t, gIsWs, flag);
  k2<<<1152, 256, 0, stream>>>(a_t, b_t, s_t);
  k3<<<NR/128, 256, 0, stream>>>(s_t, gno, bno, wp, d_out, g_t, gIsWs, flag);
}

// Round 7
// 326.985 us; speedup vs baseline: 1.1438x; 1.1438x over previous
//
#include <hip/hip_runtime.h>
#include <stdint.h>

#define N 384
#define NR (N*N)        // 147456
#define PL (NR + 64)    // padded plane stride
#define C 128
#define WSZ 16384       // 128x128 elements per weight

typedef unsigned short ushort_t;
typedef __attribute__((ext_vector_type(8))) _Float16 f16x8;
typedef __attribute__((ext_vector_type(4))) float f32x4;

// ---- fp16 converts (internal pipeline dtype) ---------------------------
__device__ __forceinline__ ushort_t f2h(float f) {
  union { _Float16 h; ushort_t u; } v; v.h = (_Float16)f; return v.u;
}
__device__ __forceinline__ void unpack8h(uint4 q, float f[8]) {
  union { uint4 q; _Float16 h[8]; } v; v.q = q;
#pragma unroll
  for (int e = 0; e < 8; ++e) f[e] = (float)v.h[e];
}
__device__ __forceinline__ uint4 pack8h(const float f[8]) {
  union { uint4 q; _Float16 h[8]; } v;
#pragma unroll
  for (int e = 0; e < 8; ++e) v.h[e] = (_Float16)f[e];
  return v.q;
}

// ---- bf16 converts (only for bf16 external-dtype fallback IO) ----------
__device__ __forceinline__ float bf2f(ushort_t u) {
  union { unsigned int i; float f; } v; v.i = ((unsigned int)u) << 16; return v.f;
}
__device__ __forceinline__ ushort_t f2bf(float f) {
  union { float f; unsigned int i; } v; v.f = f;
  unsigned int u = v.i + 0x7FFF + ((v.i >> 16) & 1);
  return (ushort_t)(u >> 16);
}
__device__ __forceinline__ void unpack8bf(uint4 q, float f[8]) {
  const unsigned int* w = (const unsigned int*)&q;
#pragma unroll
  for (int e = 0; e < 4; ++e) {
    f[2*e]   = bf2f((ushort_t)(w[e] & 0xffffu));
    f[2*e+1] = bf2f((ushort_t)(w[e] >> 16));
  }
}
__device__ __forceinline__ uint4 pack8bf(const float f[8]) {
  uint4 q;
  unsigned int* w = (unsigned int*)&q;
#pragma unroll
  for (int e = 0; e < 4; ++e)
    w[e] = (unsigned int)f2bf(f[2*e]) | ((unsigned int)f2bf(f[2*e+1]) << 16);
  return q;
}

// v_rcp: ~1 ulp, replaces the ~10-op exact-divide sequence (no fast-math)
__device__ __forceinline__ float sigmoidf_(float x) {
  return __builtin_amdgcn_rcpf(1.0f + __expf(-x));
}

// ---- dtype-dual IO helpers (isf32 is wave-uniform) ---------------------
__device__ __forceinline__ void load8f(const void* p, size_t idx, int isf32, float f[8]) {
  if (isf32) {
    const float* q = (const float*)p + idx;
    const float4 a = ((const float4*)q)[0];
    const float4 b = ((const float4*)q)[1];
    f[0]=a.x; f[1]=a.y; f[2]=a.z; f[3]=a.w;
    f[4]=b.x; f[5]=b.y; f[6]=b.z; f[7]=b.w;
  } else {
    unpack8bf(*(const uint4*)((const ushort_t*)p + idx), f);
  }
}
__device__ __forceinline__ void store8(void* p, size_t idx, int isf32, const float f[8]) {
  if (isf32) {
    float* q = (float*)p + idx;
    ((float4*)q)[0] = make_float4(f[0], f[1], f[2], f[3]);
    ((float4*)q)[1] = make_float4(f[4], f[5], f[6], f[7]);
  } else {
    *(uint4*)((ushort_t*)p + idx) = pack8bf(f);
  }
}
__device__ __forceinline__ void store1(void* p, size_t idx, int isf32, float v) {
  if (isf32) ((float*)p)[idx] = v;
  else       ((ushort_t*)p)[idx] = f2bf(v);
}

// ---- weight prep + inline dtype detection ------------------------------
__global__ void kprep(const unsigned int* __restrict__ zw,
                      const void* __restrict__ Wa1, const void* __restrict__ Wa2,
                      const void* __restrict__ Wb1, const void* __restrict__ Wb2,
                      const void* __restrict__ Wg,  const void* __restrict__ Wout,
                      ushort_t* __restrict__ wp, int* __restrict__ flag)
{
  const int t = threadIdx.x;
  __shared__ int cnt[4];
  {
    unsigned int u = zw[t];
    int e = (u >> 23) & 0xFF;
    int sane = (e >= 87 && e <= 132) ? 1 : 0;
    unsigned long long b = __ballot(sane);
    if ((t & 63) == 0) cnt[t >> 6] = __popcll(b);
  }
  __syncthreads();
  const int isf32 = ((cnt[0] + cnt[1] + cnt[2] + cnt[3]) >= 128) ? 1 : 0;
  if (blockIdx.x == 0 && t == 0) flag[0] = isf32;

  const void* src;
  switch (blockIdx.x) {
    case 0: src = Wa1; break;
    case 1: src = Wa2; break;
    case 2: src = Wb1; break;
    case 3: src = Wb2; break;
    case 4: src = Wg;  break;
    default: src = Wout; break;
  }
  ushort_t* dst = wp + (size_t)blockIdx.x * WSZ;
  for (int c = t; c < 2048; c += 256) {
    int ks = c >> 9, nf = (c >> 6) & 7, lane = c & 63;
    int quad = lane >> 4, l16 = lane & 15;
    size_t sidx = (size_t)(nf*16 + l16)*128 + ks*32 + quad*8;
    float f[8]; load8f(src, sidx, isf32, f);
    *(uint4*)(dst + (size_t)c*8) = pack8h(f);
  }
}

// ---------------- K1a: streaming LN(z) -> zn (fp16 [R][C]) --------------
// 4 threads/row, 32 elems each (32 regs); HBM-bound (113 MB). Splitting
// LN out of the projection kernel removes its serial chain + registers
// from the MFMA kernel (R6 falsified the acc-register hypothesis; arch
// pressure is weight-fragment hoisting + LN staging).
__global__ __launch_bounds__(256, 4)
void k1a(const void* __restrict__ z, const void* __restrict__ gin,
         const void* __restrict__ bin, ushort_t* __restrict__ zn,
         const int* __restrict__ flag)
{
  const int isf32 = *flag;
  const int tid = blockIdx.x * 256 + threadIdx.x;
  const int r = tid >> 2, h = tid & 3;       // 4 threads per row
  float x[4][8];
  float sum = 0.f, sq = 0.f;
#pragma unroll
  for (int j = 0; j < 4; ++j) {
    load8f(z, (size_t)r*C + h*32 + j*8, isf32, x[j]);
#pragma unroll
    for (int e = 0; e < 8; ++e) { sum += x[j][e]; sq += x[j][e]*x[j][e]; }
  }
  sum += __shfl_xor(sum, 1); sum += __shfl_xor(sum, 2);
  sq  += __shfl_xor(sq, 1);  sq  += __shfl_xor(sq, 2);
  const float mu = sum * 0.0078125f;
  const float rstd = rsqrtf(sq * 0.0078125f - mu*mu + 1e-5f);
#pragma unroll
  for (int j = 0; j < 4; ++j) {
    float ga[8], be[8];
    load8f(gin, (size_t)(h*32 + j*8), isf32, ga);
    load8f(bin, (size_t)(h*32 + j*8), isf32, be);
    float f[8];
#pragma unroll
    for (int e = 0; e < 8; ++e) f[e] = (x[j][e] - mu) * rstd * ga[e] + be[e];
    *(uint4*)(zn + (size_t)r*C + h*32 + j*8) = pack8h(f);
  }
}

// ---------------- K1b: 5 projections from zn (no LN) --------------------
// af fragments load DIRECTLY from fp16 zn (no conversion, no LN regs).
// Pair structure = R5's proven version (nh halves unroll 1, 32 acc live).
__global__ __launch_bounds__(256, 2)
void k1b(const ushort_t* __restrict__ zn, const ushort_t* __restrict__ wp,
         ushort_t* __restrict__ a_t, ushort_t* __restrict__ b_t,
         void* __restrict__ gout, ushort_t* __restrict__ g_t, int gIsWs,
         const int* __restrict__ flag)
{
  __shared__ ushort_t tb[128*72];      // 18 KB: 128 d x 64 rows (+pad to 72)
  const int t = threadIdx.x;
  const int isf32 = *flag;
  const int wave = t >> 6, lane = t & 63;
  const int quad = lane >> 4, l16 = lane & 15;
  const int rg = wave >> 1, ch = wave & 1;
  const int R0 = blockIdx.x * 64;
  const f32x4 z4 = {0.f, 0.f, 0.f, 0.f};

  // ---- A-fragments straight from zn
  f16x8 af[2][4];
#pragma unroll
  for (int mf = 0; mf < 2; ++mf) {
    const int row = R0 + rg*32 + mf*16 + l16;
#pragma unroll
    for (int ks = 0; ks < 4; ++ks)
      af[mf][ks] = *(const f16x8*)(zn + (size_t)row*C + ks*32 + quad*8);
  }

  // ---- gated pair projection: dst[d][R] = sig(z@W1^T) * (z@W2^T)
  auto pair = [&](const ushort_t* W1p, const ushort_t* W2p, ushort_t* dst) {
#pragma unroll 1
    for (int nh = 0; nh < 2; ++nh) {
      f32x4 a1[2][2], a2[2][2];
#pragma unroll
      for (int mf = 0; mf < 2; ++mf)
#pragma unroll
        for (int nn = 0; nn < 2; ++nn) { a1[mf][nn] = z4; a2[mf][nn] = z4; }
#pragma unroll
      for (int ks = 0; ks < 4; ++ks)
#pragma unroll
        for (int nn = 0; nn < 2; ++nn) {
          const size_t foff = (size_t)((ks*8 + ch*4 + nh*2 + nn)*64 + lane) * 8;
          f16x8 b1 = *(const f16x8*)(W1p + foff);
          f16x8 b2 = *(const f16x8*)(W2p + foff);
#pragma unroll
          for (int mf = 0; mf < 2; ++mf) {
            a1[mf][nn] = __builtin_amdgcn_mfma_f32_16x16x32_f16(af[mf][ks], b1, a1[mf][nn], 0, 0, 0);
            a2[mf][nn] = __builtin_amdgcn_mfma_f32_16x16x32_f16(af[mf][ks], b2, a2[mf][nn], 0, 0, 0);
          }
        }
#pragma unroll
      for (int mf = 0; mf < 2; ++mf)
#pragma unroll
        for (int nn = 0; nn < 2; ++nn)
#pragma unroll
          for (int r = 0; r < 4; ++r) {
            int rowl = rg*32 + mf*16 + quad*4 + r;       // 0..64
            int col  = ch*64 + (nh*2 + nn)*16 + l16;     // 0..128 (the d index)
            tb[col*72 + rowl] = f2h(a2[mf][nn][r] * sigmoidf_(a1[mf][nn][r]));
          }
    }
    // LDS-write visibility only; no vmcnt drain (a_t/b_t stores fly on)
    asm volatile("s_waitcnt lgkmcnt(0)" ::: "memory");
    __builtin_amdgcn_s_barrier();
#pragma unroll
    for (int i = 0; i < 4; ++i) {
      int cid = t + i*256, dl = cid >> 3, rc = cid & 7;  // 128 d x 8 chunks
      uint4 v = *(const uint4*)(tb + dl*72 + rc*8);
      *(uint4*)(dst + (size_t)dl*PL + R0 + rc*8) = v;
    }
    // tb reads consumed before the store issues (compiler lgkmcnt);
    // barrier alone protects tb reuse by the next pair.
    asm volatile("" ::: "memory");
    __builtin_amdgcn_s_barrier();
  };
  pair(wp + 0*WSZ, wp + 1*WSZ, a_t);
  pair(wp + 2*WSZ, wp + 3*WSZ, b_t);

  // ---- g = sigmoid(z@Wg^T), natural [R][d] layout
  {
    const ushort_t* Wgp = wp + 4*WSZ;
    f32x4 ag[2][4];
#pragma unroll
    for (int mf = 0; mf < 2; ++mf)
#pragma unroll
      for (int nf = 0; nf < 4; ++nf) ag[mf][nf] = z4;
#pragma unroll
    for (int ks = 0; ks < 4; ++ks)
#pragma unroll
      for (int nf = 0; nf < 4; ++nf) {
        const size_t foff = (size_t)((ks*8 + ch*4 + nf)*64 + lane) * 8;
        f16x8 b = *(const f16x8*)(Wgp + foff);
#pragma unroll
        for (int mf = 0; mf < 2; ++mf)
          ag[mf][nf] = __builtin_amdgcn_mfma_f32_16x16x32_f16(af[mf][ks], b, ag[mf][nf], 0, 0, 0);
      }
#pragma unroll
    for (int mf = 0; mf < 2; ++mf)
#pragma unroll
      for (int nf = 0; nf < 4; ++nf)
#pragma unroll
        for (int r = 0; r < 4; ++r) {
          int row = R0 + rg*32 + mf*16 + quad*4 + r;
          int col = ch*64 + nf*16 + l16;
          float v = sigmoidf_(ag[mf][nf][r]);
          size_t idx = (size_t)row*C + col;
          if (gIsWs) g_t[idx] = f2h(v);
          else       store1(gout, idx, isf32, v);
        }
  }
}

// ---------------- K2: s_d = A_d * B_d^T per channel ---------------------
// R5 version (2-phase register prefetch, lgkm-only barriers). R6's
// double-buffer variant cost +22 us -> reverted.
__global__ __launch_bounds__(256, 3)
void k2(const ushort_t* __restrict__ a_t, const ushort_t* __restrict__ b_t,
        ushort_t* __restrict__ s_t)
{
  __shared__ ushort_t As[128*64];
  __shared__ ushort_t Bs[128*64];
  const int t = threadIdx.x;
  const int wave = t >> 6, lane = t & 63;
  const int quad = lane >> 4, l16 = lane & 15;
  const int wm = wave >> 1, wn = wave & 1;
  const int lin = blockIdx.x;
  const int xcd = lin & 7, slot = lin >> 3;
  const int d = xcd + 8*(slot/9);
  const int tile = slot - (slot/9)*9;
  const int i0 = (tile/3) * 128, j0 = (tile%3) * 128;
  const size_t dbase = (size_t)d * PL;

  f32x4 acc[4][4];
  const f32x4 z4 = {0.f, 0.f, 0.f, 0.f};
#pragma unroll
  for (int mf = 0; mf < 4; ++mf)
#pragma unroll
    for (int nf = 0; nf < 4; ++nf) acc[mf][nf] = z4;

  uint4 va[4], vb[4];
#pragma unroll
  for (int j = 0; j < 4; ++j) {          // prologue: kt=0 tile
    int cid = t + j*256, row = cid >> 3, c = cid & 7;
    va[j] = *(const uint4*)(a_t + dbase + (size_t)(i0 + row)*N + c*8);
    vb[j] = *(const uint4*)(b_t + dbase + (size_t)(j0 + row)*N + c*8);
  }

  for (int kt = 0; kt < 6; ++kt) {
#pragma unroll
    for (int j = 0; j < 4; ++j) {        // stage current tile (swizzled)
      int cid = t + j*256, row = cid >> 3, c = cid & 7;
      int p = c ^ (row & 7);
      *(uint4*)(As + row*64 + p*8) = va[j];
      *(uint4*)(Bs + row*64 + p*8) = vb[j];
    }
    if (kt < 5) {
#pragma unroll
      for (int j = 0; j < 4; ++j) {      // prefetch kt+1 (flies under MFMA)
        int cid = t + j*256, row = cid >> 3, c = cid & 7;
        va[j] = *(const uint4*)(a_t + dbase + (size_t)(i0 + row)*N + (kt+1)*64 + c*8);
        vb[j] = *(const uint4*)(b_t + dbase + (size_t)(j0 + row)*N + (kt+1)*64 + c*8);
      }
    }
    asm volatile("s_waitcnt lgkmcnt(0)" ::: "memory");  // ds_writes visible
    __builtin_amdgcn_s_barrier();                       // no vmcnt drain!

#pragma unroll
    for (int ks = 0; ks < 2; ++ks) {
      f16x8 afr[4], bfr[4];
#pragma unroll
      for (int f = 0; f < 4; ++f) {
        int ra = wm*64 + f*16 + l16;
        int pa = (ks*4 + quad) ^ (ra & 7);
        afr[f] = *(const f16x8*)(As + ra*64 + pa*8);
        int rb = wn*64 + f*16 + l16;
        int pb = (ks*4 + quad) ^ (rb & 7);
        bfr[f] = *(const f16x8*)(Bs + rb*64 + pb*8);
      }
#pragma unroll
      for (int mf = 0; mf < 4; ++mf)
#pragma unroll
        for (int nf = 0; nf < 4; ++nf)
          acc[mf][nf] = __builtin_amdgcn_mfma_f32_16x16x32_f16(afr[mf], bfr[nf], acc[mf][nf], 0, 0, 0);
    }
    // frag reads consumed before MFMA issue (compiler lgkmcnt);
    // barrier alone protects As/Bs reuse next iteration.
    asm volatile("" ::: "memory");
    __builtin_amdgcn_s_barrier();
  }
#pragma unroll
  for (int mf = 0; mf < 4; ++mf)
#pragma unroll
    for (int nf = 0; nf < 4; ++nf)
#pragma unroll
      for (int r = 0; r < 4; ++r) {
        int row = wm*64 + mf*16 + quad*4 + r;
        int col = wn*64 + nf*16 + l16;
        s_t[dbase + (size_t)(i0 + row)*N + j0 + col] = f2h(acc[mf][nf][r]);
      }
}

// ---------------- K3: out = g * (LN(s) @ Wout^T) ------------------------
// R5 structure (two-pass LN, A-frags preloaded, 2 sequential nf-halves,
// lgkm-only barriers).
__global__ __launch_bounds__(256, 2)
void k3(const ushort_t* __restrict__ s_t, const void* __restrict__ gno,
        const void* __restrict__ bno, const ushort_t* __restrict__ wp,
        void* __restrict__ io, const ushort_t* __restrict__ g_t, int gIsWs,
        const int* __restrict__ flag)
{
  __shared__ ushort_t ss[128*136];
  const int t = threadIdx.x;
  const int isf32 = *flag;
  const int wave = t >> 6, lane = t & 63;
  const int quad = lane >> 4, l16 = lane & 15;
  const int R0 = blockIdx.x * 128;
  const ushort_t* Woutp = wp + 5*WSZ;

  // stage s tile [d][R] -> LDS [R][d] via 8x8 register transpose
  {
    const int dg = t >> 4, rg = t & 15;
    const int d0 = dg * 8;
    uint4 v[8];
#pragma unroll
    for (int dd = 0; dd < 8; ++dd)
      v[dd] = *(const uint4*)(s_t + (size_t)(d0 + dd)*PL + R0 + rg*8);
    const ushort_t* sv = (const ushort_t*)v;
#pragma unroll
    for (int rr0 = 0; rr0 < 8; ++rr0) {
      int rr = (rr0 + (t & 7)) & 7;          // lane stagger: kills bank conflicts
      ushort_t w[8];
#pragma unroll
      for (int dd = 0; dd < 8; ++dd) w[dd] = sv[dd*8 + rr];
      *(uint4*)(ss + (rg*8 + rr)*136 + d0) = *(const uint4*)w;
    }
  }
  asm volatile("s_waitcnt lgkmcnt(0)" ::: "memory");
  __builtin_amdgcn_s_barrier();

  // layernorm over d (2 threads per row), TWO-PASS over LDS (reg-light)
  {
    const int r = t >> 1, h = t & 1;
    float sum = 0.f, sq = 0.f;
#pragma unroll
    for (int j = 0; j < 8; ++j) {
      uint4 q = *(const uint4*)(ss + r*136 + (h*8 + j)*8);
      float f[8]; unpack8h(q, f);
#pragma unroll
      for (int e = 0; e < 8; ++e) { sum += f[e]; sq += f[e]*f[e]; }
    }
    sum += __shfl_xor(sum, 1);
    sq  += __shfl_xor(sq, 1);
    const float mu = sum * 0.0078125f;
    const float rstd = rsqrtf(sq * 0.0078125f - mu*mu + 1e-5f);
#pragma unroll
    for (int j = 0; j < 8; ++j) {
      const int g = h*8 + j;
      uint4 q = *(const uint4*)(ss + r*136 + g*8);
      float f[8], gm[8], bt[8];
      unpack8h(q, f);
      load8f(gno, (size_t)g*8, isf32, gm);
      load8f(bno, (size_t)g*8, isf32, bt);
#pragma unroll
      for (int e = 0; e < 8; ++e) f[e] = (f[e] - mu) * rstd * gm[e] + bt[e];
      *(uint4*)(ss + r*136 + g*8) = pack8h(f);
    }
  }
  asm volatile("s_waitcnt lgkmcnt(0)" ::: "memory");  // LN writes visible
  __builtin_amdgcn_s_barrier();

  // load ALL A-fragments first (16 regs), then barrier so the per-half
  // h write-back below can't race any wave's fragment reads.
  f16x8 afr[2][4];
#pragma unroll
  for (int ks = 0; ks < 4; ++ks)
#pragma unroll
    for (int mf = 0; mf < 2; ++mf) {
      int row = wave*32 + mf*16 + l16;
      afr[mf][ks] = *(const f16x8*)(ss + row*136 + (ks*4 + quad)*8);
    }
  asm volatile("s_waitcnt lgkmcnt(0)" ::: "memory");  // all frag reads done
  __builtin_amdgcn_s_barrier();

  // GEMM in two sequential nf-halves; write each half's h straight to ss
  const f32x4 z4 = {0.f, 0.f, 0.f, 0.f};
#pragma unroll 1
  for (int nh = 0; nh < 2; ++nh) {
    f32x4 acc[2][4];
#pragma unroll
    for (int mf = 0; mf < 2; ++mf)
#pragma unroll
      for (int nn = 0; nn < 4; ++nn) acc[mf][nn] = z4;
#pragma unroll
    for (int ks = 0; ks < 4; ++ks)
#pragma unroll
      for (int nn = 0; nn < 4; ++nn) {
        size_t foff = (size_t)(((ks*8 + nh*4 + nn)*64 + lane)) * 8;
        f16x8 b = *(const f16x8*)(Woutp + foff);
#pragma unroll
        for (int mf = 0; mf < 2; ++mf)
          acc[mf][nn] = __builtin_amdgcn_mfma_f32_16x16x32_f16(afr[mf][ks], b, acc[mf][nn], 0, 0, 0);
      }
#pragma unroll
    for (int mf = 0; mf < 2; ++mf)
#pragma unroll
      for (int nn = 0; nn < 4; ++nn)
#pragma unroll
        for (int r = 0; r < 4; ++r) {
          int row = wave*32 + mf*16 + quad*4 + r;
          int col = (nh*4 + nn)*16 + l16;
          ss[row*136 + col] = f2h(acc[mf][nn][r]);
        }
  }
  asm volatile("s_waitcnt lgkmcnt(0)" ::: "memory");  // h writes visible
  __builtin_amdgcn_s_barrier();

  // gated store: out = g * h, fully vectorized
#pragma unroll
  for (int i = 0; i < 8; ++i) {
    int cid = t + i*256;
    int row = cid >> 4, ch = cid & 15;
    size_t idx = (size_t)(R0 + row)*C + ch*8;
    float gf[8], hf[8], of[8];
    if (gIsWs) unpack8h(*(const uint4*)(g_t + idx), gf);
    else       load8f(io, idx, isf32, gf);
    unpack8h(*(const uint4*)(ss + row*136 + ch*8), hf);
#pragma unroll
    for (int e = 0; e < 8; ++e) of[e] = gf[e] * hf[e];
    store8(io, idx, isf32, of);
  }
}

extern "C" void kernel_launch(void* const* d_in, const int* in_sizes, int n_in,
                              void* d_out, int out_size, void* d_ws, size_t ws_size,
                              hipStream_t stream) {
  (void)in_sizes; (void)n_in; (void)out_size;
  const void* z    = d_in[0];
  const void* gin  = d_in[1];
  const void* bin  = d_in[2];
  const void* gno  = d_in[3];
  const void* bno  = d_in[4];
  const void* Wa1  = d_in[5];
  const void* Wa2  = d_in[6];
  const void* Wb1  = d_in[7];
  const void* Wb2  = d_in[8];
  const void* Wg   = d_in[9];
  const void* Wout = d_in[10];

  const size_t plane = (size_t)C * PL;                         // padded [d][R] plane
  int* flag     = (int*)d_ws;                                  // 256 B
  ushort_t* wp  = (ushort_t*)((char*)d_ws + 256);              // 6 x 32 KB
  ushort_t* a_t = wp + (size_t)6*WSZ;
  ushort_t* b_t = a_t + plane;
  ushort_t* s_t = b_t + plane;
  ushort_t* g_t = s_t + plane;
  size_t need_g = 256 + (size_t)6*WSZ*2 + (3*plane + (size_t)NR*C)*2;
  int gIsWs = (ws_size >= need_g) ? 1 : 0;

  // zn (LN'd z, fp16 [R][C], NR*C elems) ALIASES s_t: k1a writes it, k1b
  // reads it, then k2 overwrites s_t afterwards. No workspace growth.
  ushort_t* zn = s_t;

  kprep<<<6, 256, 0, stream>>>((const unsigned int*)z, Wa1, Wa2, Wb1, Wb2, Wg, Wout, wp, flag);
  k1a<<<NR*4/256, 256, 0, stream>>>(z, gin, bin, zn, flag);
  k1b<<<NR/64, 256, 0, stream>>>(zn, wp, a_t, b_t, d_out, g_t, gIsWs, flag);
  k2<<<1152, 256, 0, stream>>>(a_t, b_t, s_t);
  k3<<<NR/128, 256, 0, stream>>>(s_t, gno, bno, wp, d_out, g_t, gIsWs, flag);
}

// Round 9
// 297.513 us; speedup vs baseline: 1.2571x; 1.0991x over previous
//
#include <hip/hip_runtime.h>
#include <stdint.h>

#define N 384
#define NR (N*N)        // 147456
#define PL (NR + 64)    // padded plane stride
#define C 128
#define WSZ 16384       // 128x128 elements per weight

typedef unsigned short ushort_t;
typedef __attribute__((ext_vector_type(8))) _Float16 f16x8;
typedef __attribute__((ext_vector_type(4))) float f32x4;

// ---- fp16 converts (internal pipeline dtype) ---------------------------
__device__ __forceinline__ ushort_t f2h(float f) {
  union { _Float16 h; ushort_t u; } v; v.h = (_Float16)f; return v.u;
}
__device__ __forceinline__ void unpack8h(uint4 q, float f[8]) {
  union { uint4 q; _Float16 h[8]; } v; v.q = q;
#pragma unroll
  for (int e = 0; e < 8; ++e) f[e] = (float)v.h[e];
}
__device__ __forceinline__ uint4 pack8h(const float f[8]) {
  union { uint4 q; _Float16 h[8]; } v;
#pragma unroll
  for (int e = 0; e < 8; ++e) v.h[e] = (_Float16)f[e];
  return v.q;
}

// ---- bf16 converts (only for bf16 external-dtype fallback IO) ----------
__device__ __forceinline__ float bf2f(ushort_t u) {
  union { unsigned int i; float f; } v; v.i = ((unsigned int)u) << 16; return v.f;
}
__device__ __forceinline__ ushort_t f2bf(float f) {
  union { float f; unsigned int i; } v; v.f = f;
  unsigned int u = v.i + 0x7FFF + ((v.i >> 16) & 1);
  return (ushort_t)(u >> 16);
}
__device__ __forceinline__ void unpack8bf(uint4 q, float f[8]) {
  const unsigned int* w = (const unsigned int*)&q;
#pragma unroll
  for (int e = 0; e < 4; ++e) {
    f[2*e]   = bf2f((ushort_t)(w[e] & 0xffffu));
    f[2*e+1] = bf2f((ushort_t)(w[e] >> 16));
  }
}
__device__ __forceinline__ uint4 pack8bf(const float f[8]) {
  uint4 q;
  unsigned int* w = (unsigned int*)&q;
#pragma unroll
  for (int e = 0; e < 4; ++e)
    w[e] = (unsigned int)f2bf(f[2*e]) | ((unsigned int)f2bf(f[2*e+1]) << 16);
  return q;
}

// v_rcp: ~1 ulp, replaces the ~10-op exact-divide sequence (no fast-math)
__device__ __forceinline__ float sigmoidf_(float x) {
  return __builtin_amdgcn_rcpf(1.0f + __expf(-x));
}

// ---- dtype-dual IO helpers (isf32 is wave-uniform) ---------------------
__device__ __forceinline__ void load8f(const void* p, size_t idx, int isf32, float f[8]) {
  if (isf32) {
    const float* q = (const float*)p + idx;
    const float4 a = ((const float4*)q)[0];
    const float4 b = ((const float4*)q)[1];
    f[0]=a.x; f[1]=a.y; f[2]=a.z; f[3]=a.w;
    f[4]=b.x; f[5]=b.y; f[6]=b.z; f[7]=b.w;
  } else {
    unpack8bf(*(const uint4*)((const ushort_t*)p + idx), f);
  }
}
__device__ __forceinline__ void store8(void* p, size_t idx, int isf32, const float f[8]) {
  if (isf32) {
    float* q = (float*)p + idx;
    ((float4*)q)[0] = make_float4(f[0], f[1], f[2], f[3]);
    ((float4*)q)[1] = make_float4(f[4], f[5], f[6], f[7]);
  } else {
    *(uint4*)((ushort_t*)p + idx) = pack8bf(f);
  }
}
__device__ __forceinline__ void store1(void* p, size_t idx, int isf32, float v) {
  if (isf32) ((float*)p)[idx] = v;
  else       ((ushort_t*)p)[idx] = f2bf(v);
}

// ---------------- K0: merged weight-prep + streaming LN -----------------
// blocks 0..5: repack one weight matrix to fp16 fragment order.
// blocks 6.. : LN of 64 z-rows each (4 threads/row), write fp16 zn.
// dtype detection inline per block (removes kprep->k1a flag dependency).
__global__ __launch_bounds__(256, 4)
void k0(const unsigned int* __restrict__ zw, const void* __restrict__ z,
        const void* __restrict__ gin, const void* __restrict__ bin,
        const void* __restrict__ Wa1, const void* __restrict__ Wa2,
        const void* __restrict__ Wb1, const void* __restrict__ Wb2,
        const void* __restrict__ Wg,  const void* __restrict__ Wout,
        ushort_t* __restrict__ wp, ushort_t* __restrict__ zn,
        int* __restrict__ flag)
{
  const int t = threadIdx.x;
  __shared__ int cnt[4];
  {
    unsigned int u = zw[t];
    int e = (u >> 23) & 0xFF;
    int sane = (e >= 87 && e <= 132) ? 1 : 0;
    unsigned long long b = __ballot(sane);
    if ((t & 63) == 0) cnt[t >> 6] = __popcll(b);
  }
  __syncthreads();
  const int isf32 = ((cnt[0] + cnt[1] + cnt[2] + cnt[3]) >= 128) ? 1 : 0;
  const int bid = blockIdx.x;
  if (bid == 0 && t == 0) flag[0] = isf32;

  if (bid < 6) {
    const void* src;
    switch (bid) {
      case 0: src = Wa1; break;
      case 1: src = Wa2; break;
      case 2: src = Wb1; break;
      case 3: src = Wb2; break;
      case 4: src = Wg;  break;
      default: src = Wout; break;
    }
    ushort_t* dst = wp + (size_t)bid * WSZ;
    for (int c = t; c < 2048; c += 256) {
      int ks = c >> 9, nf = (c >> 6) & 7, lane = c & 63;
      int quad = lane >> 4, l16 = lane & 15;
      size_t sidx = (size_t)(nf*16 + l16)*128 + ks*32 + quad*8;
      float f[8]; load8f(src, sidx, isf32, f);
      *(uint4*)(dst + (size_t)c*8) = pack8h(f);
    }
    return;
  }

  // ---- streaming LN: 4 threads/row
  const int tid = (bid - 6) * 256 + t;
  const int r = tid >> 2, h = tid & 3;
  float x[4][8];
  float sum = 0.f, sq = 0.f;
#pragma unroll
  for (int j = 0; j < 4; ++j) {
    load8f(z, (size_t)r*C + h*32 + j*8, isf32, x[j]);
#pragma unroll
    for (int e = 0; e < 8; ++e) { sum += x[j][e]; sq += x[j][e]*x[j][e]; }
  }
  sum += __shfl_xor(sum, 1); sum += __shfl_xor(sum, 2);
  sq  += __shfl_xor(sq, 1);  sq  += __shfl_xor(sq, 2);
  const float mu = sum * 0.0078125f;
  const float rstd = rsqrtf(sq * 0.0078125f - mu*mu + 1e-5f);
#pragma unroll
  for (int j = 0; j < 4; ++j) {
    float ga[8], be[8];
    load8f(gin, (size_t)(h*32 + j*8), isf32, ga);
    load8f(bin, (size_t)(h*32 + j*8), isf32, be);
    float f[8];
#pragma unroll
    for (int e = 0; e < 8; ++e) f[e] = (x[j][e] - mu) * rstd * ga[e] + be[e];
    *(uint4*)(zn + (size_t)r*C + h*32 + j*8) = pack8h(f);
  }
}

// ---------------- K1b: 5 projections from zn (no LN) --------------------
// af fragments load DIRECTLY from fp16 zn. Pair structure = R5's proven
// version (nh halves unroll 1, 32 acc live).
__global__ __launch_bounds__(256, 2)
void k1b(const ushort_t* __restrict__ zn, const ushort_t* __restrict__ wp,
         ushort_t* __restrict__ a_t, ushort_t* __restrict__ b_t,
         void* __restrict__ gout, ushort_t* __restrict__ g_t, int gIsWs,
         const int* __restrict__ flag)
{
  __shared__ ushort_t tb[128*72];      // 18 KB: 128 d x 64 rows (+pad to 72)
  const int t = threadIdx.x;
  const int isf32 = *flag;
  const int wave = t >> 6, lane = t & 63;
  const int quad = lane >> 4, l16 = lane & 15;
  const int rg = wave >> 1, ch = wave & 1;
  const int R0 = blockIdx.x * 64;
  const f32x4 z4 = {0.f, 0.f, 0.f, 0.f};

  // ---- A-fragments straight from zn
  f16x8 af[2][4];
#pragma unroll
  for (int mf = 0; mf < 2; ++mf) {
    const int row = R0 + rg*32 + mf*16 + l16;
#pragma unroll
    for (int ks = 0; ks < 4; ++ks)
      af[mf][ks] = *(const f16x8*)(zn + (size_t)row*C + ks*32 + quad*8);
  }

  // ---- gated pair projection: dst[d][R] = sig(z@W1^T) * (z@W2^T)
  auto pair = [&](const ushort_t* W1p, const ushort_t* W2p, ushort_t* dst) {
#pragma unroll 1
    for (int nh = 0; nh < 2; ++nh) {
      f32x4 a1[2][2], a2[2][2];
#pragma unroll
      for (int mf = 0; mf < 2; ++mf)
#pragma unroll
        for (int nn = 0; nn < 2; ++nn) { a1[mf][nn] = z4; a2[mf][nn] = z4; }
#pragma unroll
      for (int ks = 0; ks < 4; ++ks)
#pragma unroll
        for (int nn = 0; nn < 2; ++nn) {
          const size_t foff = (size_t)((ks*8 + ch*4 + nh*2 + nn)*64 + lane) * 8;
          f16x8 b1 = *(const f16x8*)(W1p + foff);
          f16x8 b2 = *(const f16x8*)(W2p + foff);
#pragma unroll
          for (int mf = 0; mf < 2; ++mf) {
            a1[mf][nn] = __builtin_amdgcn_mfma_f32_16x16x32_f16(af[mf][ks], b1, a1[mf][nn], 0, 0, 0);
            a2[mf][nn] = __builtin_amdgcn_mfma_f32_16x16x32_f16(af[mf][ks], b2, a2[mf][nn], 0, 0, 0);
          }
        }
#pragma unroll
      for (int mf = 0; mf < 2; ++mf)
#pragma unroll
        for (int nn = 0; nn < 2; ++nn)
#pragma unroll
          for (int r = 0; r < 4; ++r) {
            int rowl = rg*32 + mf*16 + quad*4 + r;       // 0..64
            int col  = ch*64 + (nh*2 + nn)*16 + l16;     // 0..128 (the d index)
            tb[col*72 + rowl] = f2h(a2[mf][nn][r] * sigmoidf_(a1[mf][nn][r]));
          }
    }
    // LDS-write visibility only; no vmcnt drain (a_t/b_t stores fly on)
    asm volatile("s_waitcnt lgkmcnt(0)" ::: "memory");
    __builtin_amdgcn_s_barrier();
#pragma unroll
    for (int i = 0; i < 4; ++i) {
      int cid = t + i*256, dl = cid >> 3, rc = cid & 7;  // 128 d x 8 chunks
      uint4 v = *(const uint4*)(tb + dl*72 + rc*8);
      *(uint4*)(dst + (size_t)dl*PL + R0 + rc*8) = v;
    }
    // tb reads consumed before the store issues (compiler lgkmcnt);
    // barrier alone protects tb reuse by the next pair.
    asm volatile("" ::: "memory");
    __builtin_amdgcn_s_barrier();
  };
  pair(wp + 0*WSZ, wp + 1*WSZ, a_t);
  pair(wp + 2*WSZ, wp + 3*WSZ, b_t);

  // ---- g = sigmoid(z@Wg^T), natural [R][d] layout
  {
    const ushort_t* Wgp = wp + 4*WSZ;
    f32x4 ag[2][4];
#pragma unroll
    for (int mf = 0; mf < 2; ++mf)
#pragma unroll
      for (int nf = 0; nf < 4; ++nf) ag[mf][nf] = z4;
#pragma unroll
    for (int ks = 0; ks < 4; ++ks)
#pragma unroll
      for (int nf = 0; nf < 4; ++nf) {
        const size_t foff = (size_t)((ks*8 + ch*4 + nf)*64 + lane) * 8;
        f16x8 b = *(const f16x8*)(Wgp + foff);
#pragma unroll
        for (int mf = 0; mf < 2; ++mf)
          ag[mf][nf] = __builtin_amdgcn_mfma_f32_16x16x32_f16(af[mf][ks], b, ag[mf][nf], 0, 0, 0);
      }
#pragma unroll
    for (int mf = 0; mf < 2; ++mf)
#pragma unroll
      for (int nf = 0; nf < 4; ++nf)
#pragma unroll
        for (int r = 0; r < 4; ++r) {
          int row = R0 + rg*32 + mf*16 + quad*4 + r;
          int col = ch*64 + nf*16 + l16;
          float v = sigmoidf_(ag[mf][nf][r]);
          size_t idx = (size_t)row*C + col;
          if (gIsWs) g_t[idx] = f2h(v);
          else       store1(gout, idx, isf32, v);
        }
  }
}

// ---------------- K2: s_d = A_d * B_d^T per channel ---------------------
// R5 version (2-phase register prefetch, lgkm-only barriers).
__global__ __launch_bounds__(256, 3)
void k2(const ushort_t* __restrict__ a_t, const ushort_t* __restrict__ b_t,
        ushort_t* __restrict__ s_t)
{
  __shared__ ushort_t As[128*64];
  __shared__ ushort_t Bs[128*64];
  const int t = threadIdx.x;
  const int wave = t >> 6, lane = t & 63;
  const int quad = lane >> 4, l16 = lane & 15;
  const int wm = wave >> 1, wn = wave & 1;
  const int lin = blockIdx.x;
  const int xcd = lin & 7, slot = lin >> 3;
  const int d = xcd + 8*(slot/9);
  const int tile = slot - (slot/9)*9;
  const int i0 = (tile/3) * 128, j0 = (tile%3) * 128;
  const size_t dbase = (size_t)d * PL;

  f32x4 acc[4][4];
  const f32x4 z4 = {0.f, 0.f, 0.f, 0.f};
#pragma unroll
  for (int mf = 0; mf < 4; ++mf)
#pragma unroll
    for (int nf = 0; nf < 4; ++nf) acc[mf][nf] = z4;

  uint4 va[4], vb[4];
#pragma unroll
  for (int j = 0; j < 4; ++j) {          // prologue: kt=0 tile
    int cid = t + j*256, row = cid >> 3, c = cid & 7;
    va[j] = *(const uint4*)(a_t + dbase + (size_t)(i0 + row)*N + c*8);
    vb[j] = *(const uint4*)(b_t + dbase + (size_t)(j0 + row)*N + c*8);
  }

  for (int kt = 0; kt < 6; ++kt) {
#pragma unroll
    for (int j = 0; j < 4; ++j) {        // stage current tile (swizzled)
      int cid = t + j*256, row = cid >> 3, c = cid & 7;
      int p = c ^ (row & 7);
      *(uint4*)(As + row*64 + p*8) = va[j];
      *(uint4*)(Bs + row*64 + p*8) = vb[j];
    }
    if (kt < 5) {
#pragma unroll
      for (int j = 0; j < 4; ++j) {      // prefetch kt+1 (flies under MFMA)
        int cid = t + j*256, row = cid >> 3, c = cid & 7;
        va[j] = *(const uint4*)(a_t + dbase + (size_t)(i0 + row)*N + (kt+1)*64 + c*8);
        vb[j] = *(const uint4*)(b_t + dbase + (size_t)(j0 + row)*N + (kt+1)*64 + c*8);
      }
    }
    asm volatile("s_waitcnt lgkmcnt(0)" ::: "memory");  // ds_writes visible
    __builtin_amdgcn_s_barrier();                       // no vmcnt drain!

#pragma unroll
    for (int ks = 0; ks < 2; ++ks) {
      f16x8 afr[4], bfr[4];
#pragma unroll
      for (int f = 0; f < 4; ++f) {
        int ra = wm*64 + f*16 + l16;
        int pa = (ks*4 + quad) ^ (ra & 7);
        afr[f] = *(const f16x8*)(As + ra*64 + pa*8);
        int rb = wn*64 + f*16 + l16;
        int pb = (ks*4 + quad) ^ (rb & 7);
        bfr[f] = *(const f16x8*)(Bs + rb*64 + pb*8);
      }
#pragma unroll
      for (int mf = 0; mf < 4; ++mf)
#pragma unroll
        for (int nf = 0; nf < 4; ++nf)
          acc[mf][nf] = __builtin_amdgcn_mfma_f32_16x16x32_f16(afr[mf], bfr[nf], acc[mf][nf], 0, 0, 0);
    }
    // frag reads consumed before MFMA issue (compiler lgkmcnt);
    // barrier alone protects As/Bs reuse next iteration.
    asm volatile("" ::: "memory");
    __builtin_amdgcn_s_barrier();
  }
#pragma unroll
  for (int mf = 0; mf < 4; ++mf)
#pragma unroll
    for (int nf = 0; nf < 4; ++nf)
#pragma unroll
      for (int r = 0; r < 4; ++r) {
        int row = wm*64 + mf*16 + quad*4 + r;
        int col = wn*64 + nf*16 + l16;
        s_t[dbase + (size_t)(i0 + row)*N + j0 + col] = f2h(acc[mf][nf][r]);
      }
}

// ---------------- K3: out = g * (LN(s) @ Wout^T) ------------------------
// 64-row tiles (grid 2304, 18 KB LDS -> ~8 blocks/CU TLP) + LN fused into
// fragment production: stats pass computes mu/rstd only; the normalize
// write-back pass is GONE (fragments read raw s and apply LN in VALU).
__global__ __launch_bounds__(256, 2)
void k3(const ushort_t* __restrict__ s_t, const void* __restrict__ gno,
        const void* __restrict__ bno, const ushort_t* __restrict__ wp,
        void* __restrict__ io, const ushort_t* __restrict__ g_t, int gIsWs,
        const int* __restrict__ flag)
{
  __shared__ ushort_t ss[64*136];
  __shared__ float muA[64];
  __shared__ float rsA[64];
  const int t = threadIdx.x;
  const int isf32 = *flag;
  const int wave = t >> 6, lane = t & 63;
  const int quad = lane >> 4, l16 = lane & 15;
  const int R0 = blockIdx.x * 64;
  const ushort_t* Woutp = wp + 5*WSZ;

  // stage s tile [d][R0..R0+64] -> LDS [r][d] via 4x8 register transpose
  {
    const int dg = t >> 3, rg = t & 7;     // dg 0..31 (4 d each), rg 0..7 (8 r)
    const int d0 = dg * 4;
    uint4 v[4];
#pragma unroll
    for (int dd = 0; dd < 4; ++dd)
      v[dd] = *(const uint4*)(s_t + (size_t)(d0 + dd)*PL + R0 + rg*8);
    const ushort_t* sv = (const ushort_t*)v;
#pragma unroll
    for (int rr0 = 0; rr0 < 8; ++rr0) {
      int rr = (rr0 + (t & 7)) & 7;        // lane stagger
      alignas(8) ushort_t w[4];
#pragma unroll
      for (int dd = 0; dd < 4; ++dd) w[dd] = sv[dd*8 + rr];
      *(uint2*)(ss + (rg*8 + rr)*136 + d0) = *(const uint2*)w;
    }
  }
  asm volatile("s_waitcnt lgkmcnt(0)" ::: "memory");
  __builtin_amdgcn_s_barrier();

  // LN stats only (4 threads/row): mu/rstd -> LDS; NO normalize pass
  {
    const int r = t >> 2, h = t & 3;
    float sum = 0.f, sq = 0.f;
#pragma unroll
    for (int j = 0; j < 4; ++j) {
      uint4 q = *(const uint4*)(ss + r*136 + h*32 + j*8);
      float f[8]; unpack8h(q, f);
#pragma unroll
      for (int e = 0; e < 8; ++e) { sum += f[e]; sq += f[e]*f[e]; }
    }
    sum += __shfl_xor(sum, 1); sum += __shfl_xor(sum, 2);
    sq  += __shfl_xor(sq, 1);  sq  += __shfl_xor(sq, 2);
    if (h == 0) {
      const float mu = sum * 0.0078125f;
      muA[r] = mu;
      rsA[r] = rsqrtf(sq * 0.0078125f - mu*mu + 1e-5f);
    }
  }
  asm volatile("s_waitcnt lgkmcnt(0)" ::: "memory");
  __builtin_amdgcn_s_barrier();

  // fragment build: read RAW s, apply LN in f32, convert to fp16
  f16x8 afr[4];
  {
    const int frow = wave*16 + l16;        // 0..63
    const float mu_r = muA[frow];
    const float rs_r = rsA[frow];
#pragma unroll
    for (int ks = 0; ks < 4; ++ks) {
      uint4 raw = *(const uint4*)(ss + frow*136 + (ks*4 + quad)*8);
      float f[8], ga[8], be[8];
      unpack8h(raw, f);
      load8f(gno, (size_t)(ks*32 + quad*8), isf32, ga);
      load8f(bno, (size_t)(ks*32 + quad*8), isf32, be);
      union { alignas(16) _Float16 h[8]; f16x8 v; } u;
#pragma unroll
      for (int e = 0; e < 8; ++e)
        u.h[e] = (_Float16)((f[e] - mu_r) * rs_r * ga[e] + be[e]);
      afr[ks] = u.v;
    }
  }
  asm volatile("s_waitcnt lgkmcnt(0)" ::: "memory");  // all raw reads done
  __builtin_amdgcn_s_barrier();                       // before h overwrites ss

  // GEMM in two sequential nf-halves (16 acc live); h -> ss
  const f32x4 z4 = {0.f, 0.f, 0.f, 0.f};
#pragma unroll 1
  for (int nh = 0; nh < 2; ++nh) {
    f32x4 acc[4];
#pragma unroll
    for (int nn = 0; nn < 4; ++nn) acc[nn] = z4;
#pragma unroll
    for (int ks = 0; ks < 4; ++ks)
#pragma unroll
      for (int nn = 0; nn < 4; ++nn) {
        size_t foff = (size_t)(((ks*8 + nh*4 + nn)*64 + lane)) * 8;
        f16x8 b = *(const f16x8*)(Woutp + foff);
        acc[nn] = __builtin_amdgcn_mfma_f32_16x16x32_f16(afr[ks], b, acc[nn], 0, 0, 0);
      }
#pragma unroll
    for (int nn = 0; nn < 4; ++nn)
#pragma unroll
      for (int r = 0; r < 4; ++r) {
        int row = wave*16 + quad*4 + r;
        int col = (nh*4 + nn)*16 + l16;
        ss[row*136 + col] = f2h(acc[nn][r]);
      }
  }
  asm volatile("s_waitcnt lgkmcnt(0)" ::: "memory");  // h writes visible
  __builtin_amdgcn_s_barrier();

  // gated store: out = g * h, fully vectorized
#pragma unroll
  for (int i = 0; i < 4; ++i) {
    int cid = t + i*256;
    int row = cid >> 4, ch = cid & 15;
    size_t idx = (size_t)(R0 + row)*C + ch*8;
    float gf[8], hf[8], of[8];
    if (gIsWs) unpack8h(*(const uint4*)(g_t + idx), gf);
    else       load8f(io, idx, isf32, gf);
    unpack8h(*(const uint4*)(ss + row*136 + ch*8), hf);
#pragma unroll
    for (int e = 0; e < 8; ++e) of[e] = gf[e] * hf[e];
    store8(io, idx, isf32, of);
  }
}

extern "C" void kernel_launch(void* const* d_in, const int* in_sizes, int n_in,
                              void* d_out, int out_size, void* d_ws, size_t ws_size,
                              hipStream_t stream) {
  (void)in_sizes; (void)n_in; (void)out_size;
  const void* z    = d_in[0];
  const void* gin  = d_in[1];
  const void* bin  = d_in[2];
  const void* gno  = d_in[3];
  const void* bno  = d_in[4];
  const void* Wa1  = d_in[5];
  const void* Wa2  = d_in[6];
  const void* Wb1  = d_in[7];
  const void* Wb2  = d_in[8];
  const void* Wg   = d_in[9];
  const void* Wout = d_in[10];

  const size_t plane = (size_t)C * PL;                         // padded [d][R] plane
  int* flag     = (int*)d_ws;                                  // 256 B
  ushort_t* wp  = (ushort_t*)((char*)d_ws + 256);              // 6 x 32 KB
  ushort_t* a_t = wp + (size_t)6*WSZ;
  ushort_t* b_t = a_t + plane;
  ushort_t* s_t = b_t + plane;
  ushort_t* g_t = s_t + plane;
  size_t need_g = 256 + (size_t)6*WSZ*2 + (3*plane + (size_t)NR*C)*2;
  int gIsWs = (ws_size >= need_g) ? 1 : 0;

  // zn (LN'd z, fp16 [R][C]) ALIASES s_t: k0 writes it, k1b reads it,
  // then k2 overwrites s_t afterwards. No workspace growth.
  ushort_t* zn = s_t;

  k0<<<6 + NR*4/256, 256, 0, stream>>>((const unsigned int*)z, z, gin, bin,
                                       Wa1, Wa2, Wb1, Wb2, Wg, Wout, wp, zn, flag);
  k1b<<<NR/64, 256, 0, stream>>>(zn, wp, a_t, b_t, d_out, g_t, gIsWs, flag);
  k2<<<1152, 256, 0, stream>>>(a_t, b_t, s_t);
  k3<<<NR/64, 256, 0, stream>>>(s_t, gno, bno, wp, d_out, g_t, gIsWs, flag);
}

// Round 10
// 277.045 us; speedup vs baseline: 1.3500x; 1.0739x over previous
//
#include <hip/hip_runtime.h>
#include <stdint.h>

#define N 384
#define NR (N*N)        // 147456
#define PL (NR + 64)    // padded plane stride
#define C 128
#define WSZ 16384       // 128x128 elements per weight

typedef unsigned short ushort_t;
typedef __attribute__((ext_vector_type(8))) _Float16 f16x8;
typedef __attribute__((ext_vector_type(4))) float f32x4;

// ---- fp16 converts (internal pipeline dtype) ---------------------------
__device__ __forceinline__ ushort_t f2h(float f) {
  union { _Float16 h; ushort_t u; } v; v.h = (_Float16)f; return v.u;
}
__device__ __forceinline__ void unpack8h(uint4 q, float f[8]) {
  union { uint4 q; _Float16 h[8]; } v; v.q = q;
#pragma unroll
  for (int e = 0; e < 8; ++e) f[e] = (float)v.h[e];
}
__device__ __forceinline__ uint4 pack8h(const float f[8]) {
  union { uint4 q; _Float16 h[8]; } v;
#pragma unroll
  for (int e = 0; e < 8; ++e) v.h[e] = (_Float16)f[e];
  return v.q;
}

// ---- bf16 converts (only for bf16 external-dtype fallback IO) ----------
__device__ __forceinline__ float bf2f(ushort_t u) {
  union { unsigned int i; float f; } v; v.i = ((unsigned int)u) << 16; return v.f;
}
__device__ __forceinline__ ushort_t f2bf(float f) {
  union { float f; unsigned int i; } v; v.f = f;
  unsigned int u = v.i + 0x7FFF + ((v.i >> 16) & 1);
  return (ushort_t)(u >> 16);
}
__device__ __forceinline__ void unpack8bf(uint4 q, float f[8]) {
  const unsigned int* w = (const unsigned int*)&q;
#pragma unroll
  for (int e = 0; e < 4; ++e) {
    f[2*e]   = bf2f((ushort_t)(w[e] & 0xffffu));
    f[2*e+1] = bf2f((ushort_t)(w[e] >> 16));
  }
}
__device__ __forceinline__ uint4 pack8bf(const float f[8]) {
  uint4 q;
  unsigned int* w = (unsigned int*)&q;
#pragma unroll
  for (int e = 0; e < 4; ++e)
    w[e] = (unsigned int)f2bf(f[2*e]) | ((unsigned int)f2bf(f[2*e+1]) << 16);
  return q;
}

// v_rcp: ~1 ulp, replaces the ~10-op exact-divide sequence (no fast-math)
__device__ __forceinline__ float sigmoidf_(float x) {
  return __builtin_amdgcn_rcpf(1.0f + __expf(-x));
}

// ---- dtype-dual IO helpers (isf32 is wave-uniform) ---------------------
__device__ __forceinline__ void load8f(const void* p, size_t idx, int isf32, float f[8]) {
  if (isf32) {
    const float* q = (const float*)p + idx;
    const float4 a = ((const float4*)q)[0];
    const float4 b = ((const float4*)q)[1];
    f[0]=a.x; f[1]=a.y; f[2]=a.z; f[3]=a.w;
    f[4]=b.x; f[5]=b.y; f[6]=b.z; f[7]=b.w;
  } else {
    unpack8bf(*(const uint4*)((const ushort_t*)p + idx), f);
  }
}
__device__ __forceinline__ void store8(void* p, size_t idx, int isf32, const float f[8]) {
  if (isf32) {
    float* q = (float*)p + idx;
    ((float4*)q)[0] = make_float4(f[0], f[1], f[2], f[3]);
    ((float4*)q)[1] = make_float4(f[4], f[5], f[6], f[7]);
  } else {
    *(uint4*)((ushort_t*)p + idx) = pack8bf(f);
  }
}
__device__ __forceinline__ void store1(void* p, size_t idx, int isf32, float v) {
  if (isf32) ((float*)p)[idx] = v;
  else       ((ushort_t*)p)[idx] = f2bf(v);
}

// ---------------- K0: merged weight-prep + streaming LN -----------------
// blocks 0..5: repack one weight matrix to fp16 fragment order.
// blocks 6.. : LN of 32 z-rows each (8 threads/row), write fp16 zn.
// R9 spill fix: 8 threads/row -> x[2][8]=16 floats staged per thread
// (was x[4][8]=32 at VGPR_Count=32 -> 75 MB scratch round-trip; WRITE_SIZE
// showed 79 MB vs 37.7 ideal).
__global__ __launch_bounds__(256, 4)
void k0(const unsigned int* __restrict__ zw, const void* __restrict__ z,
        const void* __restrict__ gin, const void* __restrict__ bin,
        const void* __restrict__ Wa1, const void* __restrict__ Wa2,
        const void* __restrict__ Wb1, const void* __restrict__ Wb2,
        const void* __restrict__ Wg,  const void* __restrict__ Wout,
        ushort_t* __restrict__ wp, ushort_t* __restrict__ zn,
        int* __restrict__ flag)
{
  const int t = threadIdx.x;
  __shared__ int cnt[4];
  {
    unsigned int u = zw[t];
    int e = (u >> 23) & 0xFF;
    int sane = (e >= 87 && e <= 132) ? 1 : 0;
    unsigned long long b = __ballot(sane);
    if ((t & 63) == 0) cnt[t >> 6] = __popcll(b);
  }
  __syncthreads();
  const int isf32 = ((cnt[0] + cnt[1] + cnt[2] + cnt[3]) >= 128) ? 1 : 0;
  const int bid = blockIdx.x;
  if (bid == 0 && t == 0) flag[0] = isf32;

  if (bid < 6) {
    const void* src;
    switch (bid) {
      case 0: src = Wa1; break;
      case 1: src = Wa2; break;
      case 2: src = Wb1; break;
      case 3: src = Wb2; break;
      case 4: src = Wg;  break;
      default: src = Wout; break;
    }
    ushort_t* dst = wp + (size_t)bid * WSZ;
    for (int c = t; c < 2048; c += 256) {
      int ks = c >> 9, nf = (c >> 6) & 7, lane = c & 63;
      int quad = lane >> 4, l16 = lane & 15;
      size_t sidx = (size_t)(nf*16 + l16)*128 + ks*32 + quad*8;
      float f[8]; load8f(src, sidx, isf32, f);
      *(uint4*)(dst + (size_t)c*8) = pack8h(f);
    }
    return;
  }

  // ---- streaming LN: 8 threads/row, 16 elems staged per thread
  const int tid = (bid - 6) * 256 + t;
  const int r = tid >> 3, h = tid & 7;
  float x[2][8];
  float sum = 0.f, sq = 0.f;
#pragma unroll
  for (int j = 0; j < 2; ++j) {
    load8f(z, (size_t)r*C + h*16 + j*8, isf32, x[j]);
#pragma unroll
    for (int e = 0; e < 8; ++e) { sum += x[j][e]; sq += x[j][e]*x[j][e]; }
  }
  sum += __shfl_xor(sum, 1); sum += __shfl_xor(sum, 2); sum += __shfl_xor(sum, 4);
  sq  += __shfl_xor(sq, 1);  sq  += __shfl_xor(sq, 2);  sq  += __shfl_xor(sq, 4);
  const float mu = sum * 0.0078125f;
  const float rstd = rsqrtf(sq * 0.0078125f - mu*mu + 1e-5f);
#pragma unroll
  for (int j = 0; j < 2; ++j) {
    float ga[8], be[8];
    load8f(gin, (size_t)(h*16 + j*8), isf32, ga);
    load8f(bin, (size_t)(h*16 + j*8), isf32, be);
    float f[8];
#pragma unroll
    for (int e = 0; e < 8; ++e) f[e] = (x[j][e] - mu) * rstd * ga[e] + be[e];
    *(uint4*)(zn + (size_t)r*C + h*16 + j*8) = pack8h(f);
  }
}

// ---------------- K1b: 5 projections from zn (no LN) --------------------
// af fragments load DIRECTLY from fp16 zn. Pair structure = R5's proven
// version (nh halves unroll 1, 32 acc live).
__global__ __launch_bounds__(256, 2)
void k1b(const ushort_t* __restrict__ zn, const ushort_t* __restrict__ wp,
         ushort_t* __restrict__ a_t, ushort_t* __restrict__ b_t,
         void* __restrict__ gout, ushort_t* __restrict__ g_t, int gIsWs,
         const int* __restrict__ flag)
{
  __shared__ ushort_t tb[128*72];      // 18 KB: 128 d x 64 rows (+pad to 72)
  const int t = threadIdx.x;
  const int isf32 = *flag;
  const int wave = t >> 6, lane = t & 63;
  const int quad = lane >> 4, l16 = lane & 15;
  const int rg = wave >> 1, ch = wave & 1;
  const int R0 = blockIdx.x * 64;
  const f32x4 z4 = {0.f, 0.f, 0.f, 0.f};

  // ---- A-fragments straight from zn
  f16x8 af[2][4];
#pragma unroll
  for (int mf = 0; mf < 2; ++mf) {
    const int row = R0 + rg*32 + mf*16 + l16;
#pragma unroll
    for (int ks = 0; ks < 4; ++ks)
      af[mf][ks] = *(const f16x8*)(zn + (size_t)row*C + ks*32 + quad*8);
  }

  // ---- gated pair projection: dst[d][R] = sig(z@W1^T) * (z@W2^T)
  auto pair = [&](const ushort_t* W1p, const ushort_t* W2p, ushort_t* dst) {
#pragma unroll 1
    for (int nh = 0; nh < 2; ++nh) {
      f32x4 a1[2][2], a2[2][2];
#pragma unroll
      for (int mf = 0; mf < 2; ++mf)
#pragma unroll
        for (int nn = 0; nn < 2; ++nn) { a1[mf][nn] = z4; a2[mf][nn] = z4; }
#pragma unroll
      for (int ks = 0; ks < 4; ++ks)
#pragma unroll
        for (int nn = 0; nn < 2; ++nn) {
          const size_t foff = (size_t)((ks*8 + ch*4 + nh*2 + nn)*64 + lane) * 8;
          f16x8 b1 = *(const f16x8*)(W1p + foff);
          f16x8 b2 = *(const f16x8*)(W2p + foff);
#pragma unroll
          for (int mf = 0; mf < 2; ++mf) {
            a1[mf][nn] = __builtin_amdgcn_mfma_f32_16x16x32_f16(af[mf][ks], b1, a1[mf][nn], 0, 0, 0);
            a2[mf][nn] = __builtin_amdgcn_mfma_f32_16x16x32_f16(af[mf][ks], b2, a2[mf][nn], 0, 0, 0);
          }
        }
#pragma unroll
      for (int mf = 0; mf < 2; ++mf)
#pragma unroll
        for (int nn = 0; nn < 2; ++nn)
#pragma unroll
          for (int r = 0; r < 4; ++r) {
            int rowl = rg*32 + mf*16 + quad*4 + r;       // 0..64
            int col  = ch*64 + (nh*2 + nn)*16 + l16;     // 0..128 (the d index)
            tb[col*72 + rowl] = f2h(a2[mf][nn][r] * sigmoidf_(a1[mf][nn][r]));
          }
    }
    // LDS-write visibility only; no vmcnt drain (a_t/b_t stores fly on)
    asm volatile("s_waitcnt lgkmcnt(0)" ::: "memory");
    __builtin_amdgcn_s_barrier();
#pragma unroll
    for (int i = 0; i < 4; ++i) {
      int cid = t + i*256, dl = cid >> 3, rc = cid & 7;  // 128 d x 8 chunks
      uint4 v = *(const uint4*)(tb + dl*72 + rc*8);
      *(uint4*)(dst + (size_t)dl*PL + R0 + rc*8) = v;
    }
    // tb reads consumed before the store issues (compiler lgkmcnt);
    // barrier alone protects tb reuse by the next pair.
    asm volatile("" ::: "memory");
    __builtin_amdgcn_s_barrier();
  };
  pair(wp + 0*WSZ, wp + 1*WSZ, a_t);
  pair(wp + 2*WSZ, wp + 3*WSZ, b_t);

  // ---- g = sigmoid(z@Wg^T), natural [R][d] layout
  {
    const ushort_t* Wgp = wp + 4*WSZ;
    f32x4 ag[2][4];
#pragma unroll
    for (int mf = 0; mf < 2; ++mf)
#pragma unroll
      for (int nf = 0; nf < 4; ++nf) ag[mf][nf] = z4;
#pragma unroll
    for (int ks = 0; ks < 4; ++ks)
#pragma unroll
      for (int nf = 0; nf < 4; ++nf) {
        const size_t foff = (size_t)((ks*8 + ch*4 + nf)*64 + lane) * 8;
        f16x8 b = *(const f16x8*)(Wgp + foff);
#pragma unroll
        for (int mf = 0; mf < 2; ++mf)
          ag[mf][nf] = __builtin_amdgcn_mfma_f32_16x16x32_f16(af[mf][ks], b, ag[mf][nf], 0, 0, 0);
      }
#pragma unroll
    for (int mf = 0; mf < 2; ++mf)
#pragma unroll
      for (int nf = 0; nf < 4; ++nf)
#pragma unroll
        for (int r = 0; r < 4; ++r) {
          int row = R0 + rg*32 + mf*16 + quad*4 + r;
          int col = ch*64 + nf*16 + l16;
          float v = sigmoidf_(ag[mf][nf][r]);
          size_t idx = (size_t)row*C + col;
          if (gIsWs) g_t[idx] = f2h(v);
          else       store1(gout, idx, isf32, v);
        }
  }
}

// ---------------- K2: s_d = A_d * B_d^T per channel ---------------------
// R5 version (2-phase register prefetch, lgkm-only barriers).
__global__ __launch_bounds__(256, 3)
void k2(const ushort_t* __restrict__ a_t, const ushort_t* __restrict__ b_t,
        ushort_t* __restrict__ s_t)
{
  __shared__ ushort_t As[128*64];
  __shared__ ushort_t Bs[128*64];
  const int t = threadIdx.x;
  const int wave = t >> 6, lane = t & 63;
  const int quad = lane >> 4, l16 = lane & 15;
  const int wm = wave >> 1, wn = wave & 1;
  const int lin = blockIdx.x;
  const int xcd = lin & 7, slot = lin >> 3;
  const int d = xcd + 8*(slot/9);
  const int tile = slot - (slot/9)*9;
  const int i0 = (tile/3) * 128, j0 = (tile%3) * 128;
  const size_t dbase = (size_t)d * PL;

  f32x4 acc[4][4];
  const f32x4 z4 = {0.f, 0.f, 0.f, 0.f};
#pragma unroll
  for (int mf = 0; mf < 4; ++mf)
#pragma unroll
    for (int nf = 0; nf < 4; ++nf) acc[mf][nf] = z4;

  uint4 va[4], vb[4];
#pragma unroll
  for (int j = 0; j < 4; ++j) {          // prologue: kt=0 tile
    int cid = t + j*256, row = cid >> 3, c = cid & 7;
    va[j] = *(const uint4*)(a_t + dbase + (size_t)(i0 + row)*N + c*8);
    vb[j] = *(const uint4*)(b_t + dbase + (size_t)(j0 + row)*N + c*8);
  }

  for (int kt = 0; kt < 6; ++kt) {
#pragma unroll
    for (int j = 0; j < 4; ++j) {        // stage current tile (swizzled)
      int cid = t + j*256, row = cid >> 3, c = cid & 7;
      int p = c ^ (row & 7);
      *(uint4*)(As + row*64 + p*8) = va[j];
      *(uint4*)(Bs + row*64 + p*8) = vb[j];
    }
    if (kt < 5) {
#pragma unroll
      for (int j = 0; j < 4; ++j) {      // prefetch kt+1 (flies under MFMA)
        int cid = t + j*256, row = cid >> 3, c = cid & 7;
        va[j] = *(const uint4*)(a_t + dbase + (size_t)(i0 + row)*N + (kt+1)*64 + c*8);
        vb[j] = *(const uint4*)(b_t + dbase + (size_t)(j0 + row)*N + (kt+1)*64 + c*8);
      }
    }
    asm volatile("s_waitcnt lgkmcnt(0)" ::: "memory");  // ds_writes visible
    __builtin_amdgcn_s_barrier();                       // no vmcnt drain!

#pragma unroll
    for (int ks = 0; ks < 2; ++ks) {
      f16x8 afr[4], bfr[4];
#pragma unroll
      for (int f = 0; f < 4; ++f) {
        int ra = wm*64 + f*16 + l16;
        int pa = (ks*4 + quad) ^ (ra & 7);
        afr[f] = *(const f16x8*)(As + ra*64 + pa*8);
        int rb = wn*64 + f*16 + l16;
        int pb = (ks*4 + quad) ^ (rb & 7);
        bfr[f] = *(const f16x8*)(Bs + rb*64 + pb*8);
      }
#pragma unroll
      for (int mf = 0; mf < 4; ++mf)
#pragma unroll
        for (int nf = 0; nf < 4; ++nf)
          acc[mf][nf] = __builtin_amdgcn_mfma_f32_16x16x32_f16(afr[mf], bfr[nf], acc[mf][nf], 0, 0, 0);
    }
    // frag reads consumed before MFMA issue (compiler lgkmcnt);
    // barrier alone protects As/Bs reuse next iteration.
    asm volatile("" ::: "memory");
    __builtin_amdgcn_s_barrier();
  }
#pragma unroll
  for (int mf = 0; mf < 4; ++mf)
#pragma unroll
    for (int nf = 0; nf < 4; ++nf)
#pragma unroll
      for (int r = 0; r < 4; ++r) {
        int row = wm*64 + mf*16 + quad*4 + r;
        int col = wn*64 + nf*16 + l16;
        s_t[dbase + (size_t)(i0 + row)*N + j0 + col] = f2h(acc[mf][nf][r]);
      }
}

// ---------------- K3: out = g * (LN(s) @ Wout^T) ------------------------
// 64-row tiles (grid 2304, 18 KB LDS) + LN fused into fragment production
// (stats pass computes mu/rstd only; fragments read raw s, apply LN in
// VALU). [R9: 70 -> out of top-5; absmax improved 0.027 -> 0.008]
__global__ __launch_bounds__(256, 2)
void k3(const ushort_t* __restrict__ s_t, const void* __restrict__ gno,
        const void* __restrict__ bno, const ushort_t* __restrict__ wp,
        void* __restrict__ io, const ushort_t* __restrict__ g_t, int gIsWs,
        const int* __restrict__ flag)
{
  __shared__ ushort_t ss[64*136];
  __shared__ float muA[64];
  __shared__ float rsA[64];
  const int t = threadIdx.x;
  const int isf32 = *flag;
  const int wave = t >> 6, lane = t & 63;
  const int quad = lane >> 4, l16 = lane & 15;
  const int R0 = blockIdx.x * 64;
  const ushort_t* Woutp = wp + 5*WSZ;

  // stage s tile [d][R0..R0+64] -> LDS [r][d] via 4x8 register transpose
  {
    const int dg = t >> 3, rg = t & 7;     // dg 0..31 (4 d each), rg 0..7 (8 r)
    const int d0 = dg * 4;
    uint4 v[4];
#pragma unroll
    for (int dd = 0; dd < 4; ++dd)
      v[dd] = *(const uint4*)(s_t + (size_t)(d0 + dd)*PL + R0 + rg*8);
    const ushort_t* sv = (const ushort_t*)v;
#pragma unroll
    for (int rr0 = 0; rr0 < 8; ++rr0) {
      int rr = (rr0 + (t & 7)) & 7;        // lane stagger
      alignas(8) ushort_t w[4];
#pragma unroll
      for (int dd = 0; dd < 4; ++dd) w[dd] = sv[dd*8 + rr];
      *(uint2*)(ss + (rg*8 + rr)*136 + d0) = *(const uint2*)w;
    }
  }
  asm volatile("s_waitcnt lgkmcnt(0)" ::: "memory");
  __builtin_amdgcn_s_barrier();

  // LN stats only (4 threads/row): mu/rstd -> LDS; NO normalize pass
  {
    const int r = t >> 2, h = t & 3;
    float sum = 0.f, sq = 0.f;
#pragma unroll
    for (int j = 0; j < 4; ++j) {
      uint4 q = *(const uint4*)(ss + r*136 + h*32 + j*8);
      float f[8]; unpack8h(q, f);
#pragma unroll
      for (int e = 0; e < 8; ++e) { sum += f[e]; sq += f[e]*f[e]; }
    }
    sum += __shfl_xor(sum, 1); sum += __shfl_xor(sum, 2);
    sq  += __shfl_xor(sq, 1);  sq  += __shfl_xor(sq, 2);
    if (h == 0) {
      const float mu = sum * 0.0078125f;
      muA[r] = mu;
      rsA[r] = rsqrtf(sq * 0.0078125f - mu*mu + 1e-5f);
    }
  }
  asm volatile("s_waitcnt lgkmcnt(0)" ::: "memory");
  __builtin_amdgcn_s_barrier();

  // fragment build: read RAW s, apply LN in f32, convert to fp16
  f16x8 afr[4];
  {
    const int frow = wave*16 + l16;        // 0..63
    const float mu_r = muA[frow];
    const float rs_r = rsA[frow];
#pragma unroll
    for (int ks = 0; ks < 4; ++ks) {
      uint4 raw = *(const uint4*)(ss + frow*136 + (ks*4 + quad)*8);
      float f[8], ga[8], be[8];
      unpack8h(raw, f);
      load8f(gno, (size_t)(ks*32 + quad*8), isf32, ga);
      load8f(bno, (size_t)(ks*32 + quad*8), isf32, be);
      union { alignas(16) _Float16 h[8]; f16x8 v; } u;
#pragma unroll
      for (int e = 0; e < 8; ++e)
        u.h[e] = (_Float16)((f[e] - mu_r) * rs_r * ga[e] + be[e]);
      afr[ks] = u.v;
    }
  }
  asm volatile("s_waitcnt lgkmcnt(0)" ::: "memory");  // all raw reads done
  __builtin_amdgcn_s_barrier();                       // before h overwrites ss

  // GEMM in two sequential nf-halves (16 acc live); h -> ss
  const f32x4 z4 = {0.f, 0.f, 0.f, 0.f};
#pragma unroll 1
  for (int nh = 0; nh < 2; ++nh) {
    f32x4 acc[4];
#pragma unroll
    for (int nn = 0; nn < 4; ++nn) acc[nn] = z4;
#pragma unroll
    for (int ks = 0; ks < 4; ++ks)
#pragma unroll
      for (int nn = 0; nn < 4; ++nn) {
        size_t foff = (size_t)(((ks*8 + nh*4 + nn)*64 + lane)) * 8;
        f16x8 b = *(const f16x8*)(Woutp + foff);
        acc[nn] = __builtin_amdgcn_mfma_f32_16x16x32_f16(afr[ks], b, acc[nn], 0, 0, 0);
      }
#pragma unroll
    for (int nn = 0; nn < 4; ++nn)
#pragma unroll
      for (int r = 0; r < 4; ++r) {
        int row = wave*16 + quad*4 + r;
        int col = (nh*4 + nn)*16 + l16;
        ss[row*136 + col] = f2h(acc[nn][r]);
      }
  }
  asm volatile("s_waitcnt lgkmcnt(0)" ::: "memory");  // h writes visible
  __builtin_amdgcn_s_barrier();

  // gated store: out = g * h, fully vectorized
#pragma unroll
  for (int i = 0; i < 4; ++i) {
    int cid = t + i*256;
    int row = cid >> 4, ch = cid & 15;
    size_t idx = (size_t)(R0 + row)*C + ch*8;
    float gf[8], hf[8], of[8];
    if (gIsWs) unpack8h(*(const uint4*)(g_t + idx), gf);
    else       load8f(io, idx, isf32, gf);
    unpack8h(*(const uint4*)(ss + row*136 + ch*8), hf);
#pragma unroll
    for (int e = 0; e < 8; ++e) of[e] = gf[e] * hf[e];
    store8(io, idx, isf32, of);
  }
}

extern "C" void kernel_launch(void* const* d_in, const int* in_sizes, int n_in,
                              void* d_out, int out_size, void* d_ws, size_t ws_size,
                              hipStream_t stream) {
  (void)in_sizes; (void)n_in; (void)out_size;
  const void* z    = d_in[0];
  const void* gin  = d_in[1];
  const void* bin  = d_in[2];
  const void* gno  = d_in[3];
  const void* bno  = d_in[4];
  const void* Wa1  = d_in[5];
  const void* Wa2  = d_in[6];
  const void* Wb1  = d_in[7];
  const void* Wb2  = d_in[8];
  const void* Wg   = d_in[9];
  const void* Wout = d_in[10];

  const size_t plane = (size_t)C * PL;                         // padded [d][R] plane
  int* flag     = (int*)d_ws;                                  // 256 B
  ushort_t* wp  = (ushort_t*)((char*)d_ws + 256);              // 6 x 32 KB
  ushort_t* a_t = wp + (size_t)6*WSZ;
  ushort_t* b_t = a_t + plane;
  ushort_t* s_t = b_t + plane;
  ushort_t* g_t = s_t + plane;
  size_t need_g = 256 + (size_t)6*WSZ*2 + (3*plane + (size_t)NR*C)*2;
  int gIsWs = (ws_size >= need_g) ? 1 : 0;

  // zn (LN'd z, fp16 [R][C]) ALIASES s_t: k0 writes it, k1b reads it,
  // then k2 overwrites s_t afterwards. No workspace growth.
  ushort_t* zn = s_t;

  k0<<<6 + NR*8/256, 256, 0, stream>>>((const unsigned int*)z, z, gin, bin,
                                       Wa1, Wa2, Wb1, Wb2, Wg, Wout, wp, zn, flag);
  k1b<<<NR/64, 256, 0, stream>>>(zn, wp, a_t, b_t, d_out, g_t, gIsWs, flag);
  k2<<<1152, 256, 0, stream>>>(a_t, b_t, s_t);
  k3<<<NR/64, 256, 0, stream>>>(s_t, gno, bno, wp, d_out, g_t, gIsWs, flag);
}